// Round 2
// baseline (1681.575 us; speedup 1.0000x reference)
//
#include <hip/hip_runtime.h>
#include <hip/hip_bf16.h>
#include <stdint.h>

// ---------------- constants ----------------
#define NN 50000
#define EE 800000
#define HD 128

typedef __attribute__((ext_vector_type(8))) short s8v;   // 8 bf16 (4 VGPRs) mfma A/B frag
typedef __attribute__((ext_vector_type(4))) short s4v;   // 4 bf16 (8B)
typedef __attribute__((ext_vector_type(4))) float f32x4; // mfma C/D frag

__device__ inline float b2f(short s) {
    unsigned u = ((unsigned)(unsigned short)s) << 16;
    return __builtin_bit_cast(float, u);
}
__device__ inline short bf16r(float f) {
    unsigned u = __builtin_bit_cast(unsigned, f);
    unsigned r = (u + 0x7fffu + ((u >> 16) & 1u)) >> 16;
    return (short)r;
}
__device__ inline float fsilu(float v) { return v / (1.f + __expf(-v)); }

// flag-dependent raw loads
__device__ inline float ldw(const void* p, long i, bool f32) {
    return f32 ? ((const float*)p)[i] : b2f(((const short*)p)[i]);
}
__device__ inline short ldb(const void* p, long i, bool f32) {
    return f32 ? bf16r(((const float*)p)[i]) : ((const short*)p)[i];
}

// ---------------- dtype detection ----------------
// flags[0] = 1 if float tensors are fp32 (else bf16); flags[1] = 1 if edge_index is int64
__global__ void detect_kernel(const unsigned* __restrict__ h_raw,
                              const unsigned* __restrict__ ei_raw, int* flags) {
    __shared__ int cnt_f32, cnt_nz;
    int t = threadIdx.x;
    if (t == 0) { cnt_f32 = 0; cnt_nz = 0; }
    __syncthreads();
    unsigned u = h_raw[t];
    unsigned ex = (u >> 23) & 0xFFu;
    int isf = (ex >= 100u && ex <= 150u) ? 1 : 0;  // fp32 N(0,1) exponent range
    unsigned w = ei_raw[2 * t + 1];                // high word if int64, a value if int32
    int nz = (w != 0u) ? 1 : 0;
    atomicAdd(&cnt_f32, isf);
    atomicAdd(&cnt_nz, nz);
    __syncthreads();
    if (t == 0) {
        flags[0] = (cnt_f32 >= 128) ? 1 : 0;
        flags[1] = (cnt_nz < 8) ? 1 : 0;
    }
}

// ---------------- canonicalize big arrays ----------------
// hc: N*128 bf16; eic: 2*E int32 (row then col); distf: E fp32; xf: N*3 fp32
__global__ void convert_kernel(const void* __restrict__ h, const void* __restrict__ x,
                               const void* __restrict__ ei, const void* __restrict__ dist,
                               const int* __restrict__ flags,
                               short* __restrict__ hc, int* __restrict__ eic,
                               float* __restrict__ distf, float* __restrict__ xf) {
    bool f32 = flags[0] != 0, i64 = flags[1] != 0;
    long id = (long)blockIdx.x * 256 + threadIdx.x;
    if (id < 6400000L) { hc[id] = ldb(h, id, f32); return; }
    id -= 6400000L;
    if (id < 1600000L) {
        eic[id] = i64 ? (int)((const long long*)ei)[id] : ((const int*)ei)[id];
        return;
    }
    id -= 1600000L;
    if (id < 800000L) { distf[id] = ldw(dist, id, f32); return; }
    id -= 800000L;
    if (id < 150000L) { xf[id] = ldw(x, id, f32); }
}

// ---------------- weights transpose + bias canonicalize ----------------
// we1t: [128][264] (K=257 pad 264), we2t/wc1t/wn2t: [128][128], wn1t: [128][256]
// biasbuf: be1[0] be2[128] bc1[256] wa[384] wc2[512] ba[640] bn1[768] bn2[896]
//          gamma[1024] beta[1152] w256(We1 row 256)[1280]
__global__ void prep_weights(const void* we1, const void* we2, const void* wc1,
                             const void* wn1, const void* wn2,
                             const void* be1, const void* be2, const void* bc1,
                             const void* wa, const void* ba, const void* wc2,
                             const void* bn1, const void* bn2,
                             const void* gmma, const void* beta,
                             const int* __restrict__ flags,
                             short* __restrict__ we1t, short* __restrict__ we2t,
                             short* __restrict__ wc1t, short* __restrict__ wn1t,
                             short* __restrict__ wn2t, float* __restrict__ biasbuf) {
    bool f32 = flags[0] != 0;
    int b = blockIdx.x, t = threadIdx.x;
    if (b < 640) {
        int m = b >> 7, j = b & 127;
        switch (m) {
            case 0: for (int k = t; k < 257; k += 256) we1t[j * 264 + k] = ldb(we1, k * 128 + j, f32); break;
            case 1: if (t < 128) we2t[j * 128 + t] = ldb(we2, t * 128 + j, f32); break;
            case 2: if (t < 128) wc1t[j * 128 + t] = ldb(wc1, t * 128 + j, f32); break;
            case 3: wn1t[j * 256 + t] = ldb(wn1, t * 128 + j, f32); break;
            case 4: if (t < 128) wn2t[j * 128 + t] = ldb(wn2, t * 128 + j, f32); break;
        }
    } else if (t < 128) {
        biasbuf[t]         = ldw(be1, t, f32);
        biasbuf[128 + t]   = ldw(be2, t, f32);
        biasbuf[256 + t]   = ldw(bc1, t, f32);
        biasbuf[384 + t]   = ldw(wa, t, f32);
        biasbuf[512 + t]   = ldw(wc2, t, f32);
        biasbuf[768 + t]   = ldw(bn1, t, f32);
        biasbuf[896 + t]   = ldw(bn2, t, f32);
        biasbuf[1024 + t]  = ldw(gmma, t, f32);
        biasbuf[1152 + t]  = ldw(beta, t, f32);
        biasbuf[1280 + t]  = ldw(we1, 256 * 128 + t, f32);
        if (t == 0) biasbuf[640] = ldw(ba, 0, f32);
    }
}

// ---------------- fused edge kernel ----------------
// block = 256 thr = 4 waves, 64 edges/block; wave w owns edges [16w,16w+16)
__global__ __launch_bounds__(256, 2)
void edge_kernel(const short* __restrict__ hc, const int* __restrict__ eic,
                 const float* __restrict__ distf, const float* __restrict__ xf,
                 const short* __restrict__ we1t, const short* __restrict__ we2t,
                 const short* __restrict__ wc1t, const float* __restrict__ biasbuf,
                 float* __restrict__ aggMsg, float* __restrict__ aggCoord) {
    __shared__ short feat[64][264];    // [edge][k0..256]: h[row]++h[col], +8 pad
    __shared__ short msgbuf[64][136];  // per-edge message tile (reused msg1 -> msg2)
    __shared__ float s_dist[64];
    __shared__ float s_rel[64][3];
    __shared__ int   s_col[64];
    __shared__ float s_be1[128], s_be2[128], s_bc1[128], s_wa[128], s_w256[128], s_wc2[128];
    __shared__ float s_ba;

    const int tid = threadIdx.x;
    const int e0 = blockIdx.x * 64;

    if (tid < 64) {
        int e = e0 + tid;
        int r = eic[e], c = eic[EE + e];
        s_col[tid] = c;
        s_dist[tid] = distf[e];
        #pragma unroll
        for (int i = 0; i < 3; i++) s_rel[tid][i] = xf[r * 3 + i] - xf[c * 3 + i];
    }
    if (tid < 128) {
        s_be1[tid] = biasbuf[tid];
        s_be2[tid] = biasbuf[128 + tid];
        s_bc1[tid] = biasbuf[256 + tid];
        s_wa[tid]  = biasbuf[384 + tid];
        s_wc2[tid] = biasbuf[512 + tid];
        s_w256[tid] = biasbuf[1280 + tid];
    }
    if (tid == 0) s_ba = biasbuf[640];

    // gather feat tile: 128 segments (edge,half) x 16 lanes x 16B
    {
        int lane16 = tid & 15, grp = tid >> 4;
        for (int s = grp; s < 128; s += 16) {
            int e = s >> 1, half = s & 1;
            int idx = half ? eic[EE + e0 + e] : eic[e0 + e];
            uint4 v = ((const uint4*)(hc + (long)idx * 128))[lane16];
            *(uint4*)&feat[e][half * 128 + lane16 * 8] = v;
        }
    }
    __syncthreads();

    const int lane = tid & 63;
    const int wid  = tid >> 6;
    const int t16 = lane & 15, q = lane >> 4;
    const int eRow = wid * 16 + t16;   // this lane's edge (B-frag n AND C-layout col)
    const int kq = q * 8;

    // ---- GEMM1': msg1[j][e] = silu(We1T . featT + be1), K=257 ----
    f32x4 acc[8];
    #pragma unroll
    for (int mt = 0; mt < 8; mt++) acc[mt] = (f32x4){0.f, 0.f, 0.f, 0.f};
    for (int k0 = 0; k0 < 256; k0 += 32) {
        s8v bf = *(const s8v*)&feat[eRow][k0 + kq];
        #pragma unroll
        for (int mt = 0; mt < 8; mt++) {
            s8v af = *(const s8v*)(we1t + (mt * 16 + t16) * 264 + k0 + kq);
            acc[mt] = __builtin_amdgcn_mfma_f32_16x16x32_bf16(af, bf, acc[mt], 0, 0, 0);
        }
    }
    float distE = s_dist[eRow];
    #pragma unroll
    for (int mt = 0; mt < 8; mt++) {
        s4v pk;
        #pragma unroll
        for (int r = 0; r < 4; r++) {
            int j = mt * 16 + q * 4 + r;
            float v = acc[mt][r] + distE * s_w256[j] + s_be1[j];
            pk[r] = bf16r(fsilu(v));
        }
        *(s4v*)&msgbuf[eRow][mt * 16 + q * 4] = pk;
    }

    // ---- GEMM2': msg[j][e] = We2T . msg1 + be2 ----
    f32x4 acc2[8];
    #pragma unroll
    for (int mt = 0; mt < 8; mt++) acc2[mt] = (f32x4){0.f, 0.f, 0.f, 0.f};
    for (int k0 = 0; k0 < 128; k0 += 32) {
        s8v bf = *(const s8v*)&msgbuf[eRow][k0 + kq];
        #pragma unroll
        for (int mt = 0; mt < 8; mt++) {
            s8v af = *(const s8v*)(we2t + (mt * 16 + t16) * 128 + k0 + kq);
            acc2[mt] = __builtin_amdgcn_mfma_f32_16x16x32_bf16(af, bf, acc2[mt], 0, 0, 0);
        }
    }
    // attention: sigmoid(msg . Wa + ba), then msg *= attn
    float part = 0.f;
    #pragma unroll
    for (int mt = 0; mt < 8; mt++) {
        #pragma unroll
        for (int r = 0; r < 4; r++) {
            int j = mt * 16 + q * 4 + r;
            acc2[mt][r] += s_be2[j];
            part += acc2[mt][r] * s_wa[j];
        }
    }
    part += __shfl_xor(part, 16);
    part += __shfl_xor(part, 32);
    float attn = 1.f / (1.f + __expf(-(part + s_ba)));
    int colE = s_col[eRow];
    #pragma unroll
    for (int mt = 0; mt < 8; mt++) {
        s4v pk;
        #pragma unroll
        for (int r = 0; r < 4; r++) {
            float v = acc2[mt][r] * attn;
            pk[r] = bf16r(v);
            unsafeAtomicAdd(&aggMsg[(long)colE * 128 + mt * 16 + q * 4 + r], v);
        }
        *(s4v*)&msgbuf[eRow][mt * 16 + q * 4] = pk;  // same wave's rows only -> no barrier
    }

    // ---- GEMM3': coord_w = silu(Wc1T . msg + bc1) . Wc2 ----
    f32x4 acc3[8];
    #pragma unroll
    for (int mt = 0; mt < 8; mt++) acc3[mt] = (f32x4){0.f, 0.f, 0.f, 0.f};
    for (int k0 = 0; k0 < 128; k0 += 32) {
        s8v bf = *(const s8v*)&msgbuf[eRow][k0 + kq];
        #pragma unroll
        for (int mt = 0; mt < 8; mt++) {
            s8v af = *(const s8v*)(wc1t + (mt * 16 + t16) * 128 + k0 + kq);
            acc3[mt] = __builtin_amdgcn_mfma_f32_16x16x32_bf16(af, bf, acc3[mt], 0, 0, 0);
        }
    }
    float part2 = 0.f;
    #pragma unroll
    for (int mt = 0; mt < 8; mt++) {
        #pragma unroll
        for (int r = 0; r < 4; r++) {
            int j = mt * 16 + q * 4 + r;
            part2 += fsilu(acc3[mt][r] + s_bc1[j]) * s_wc2[j];
        }
    }
    part2 += __shfl_xor(part2, 16);
    part2 += __shfl_xor(part2, 32);
    if (q == 0) {
        #pragma unroll
        for (int i = 0; i < 3; i++)
            unsafeAtomicAdd(&aggCoord[(long)colE * 3 + i], s_rel[eRow][i] * part2);
    }
}

// ---------------- fused node kernel: node MLP + residual + LayerNorm ----------------
__global__ __launch_bounds__(256, 2)
void node_kernel(const short* __restrict__ hc, const float* __restrict__ aggMsg,
                 const short* __restrict__ wn1t, const short* __restrict__ wn2t,
                 const float* __restrict__ biasbuf, const int* __restrict__ flags,
                 void* __restrict__ out) {
    __shared__ short feat[64][264];   // [node][h(128) ++ aggMsg(128)]
    __shared__ short mid[64][136];
    __shared__ float s_bn1[128], s_bn2[128], s_g[128], s_b[128];

    const int tid = threadIdx.x;
    const int n0 = blockIdx.x * 64;
    const bool outf32 = flags[0] != 0;

    if (tid < 128) {
        s_bn1[tid] = biasbuf[768 + tid];
        s_bn2[tid] = biasbuf[896 + tid];
        s_g[tid]   = biasbuf[1024 + tid];
        s_b[tid]   = biasbuf[1152 + tid];
    }
    {
        int lane16 = tid & 15, grp = tid >> 4;
        for (int s = grp; s < 64; s += 16) {
            int node = n0 + s; if (node >= NN) node = 0;
            uint4 v = ((const uint4*)(hc + (long)node * 128))[lane16];
            *(uint4*)&feat[s][lane16 * 8] = v;
        }
    }
    for (int s = tid; s < 64 * 32; s += 256) {
        int e = s >> 5, k4 = s & 31;
        int node = n0 + e; if (node >= NN) node = 0;
        float4 v = ((const float4*)(aggMsg + (long)node * 128))[k4];
        s4v pk = {bf16r(v.x), bf16r(v.y), bf16r(v.z), bf16r(v.w)};
        *(s4v*)&feat[e][128 + k4 * 4] = pk;
    }
    __syncthreads();

    const int lane = tid & 63;
    const int wid  = tid >> 6;
    const int t16 = lane & 15, q = lane >> 4;
    const int eRow = wid * 16 + t16;
    const int kq = q * 8;

    // GEMM1'': silu(Wn1T . featT + bn1), K=256
    f32x4 acc[8];
    #pragma unroll
    for (int mt = 0; mt < 8; mt++) acc[mt] = (f32x4){0.f, 0.f, 0.f, 0.f};
    for (int k0 = 0; k0 < 256; k0 += 32) {
        s8v bf = *(const s8v*)&feat[eRow][k0 + kq];
        #pragma unroll
        for (int mt = 0; mt < 8; mt++) {
            s8v af = *(const s8v*)(wn1t + (mt * 16 + t16) * 256 + k0 + kq);
            acc[mt] = __builtin_amdgcn_mfma_f32_16x16x32_bf16(af, bf, acc[mt], 0, 0, 0);
        }
    }
    #pragma unroll
    for (int mt = 0; mt < 8; mt++) {
        s4v pk;
        #pragma unroll
        for (int r = 0; r < 4; r++) {
            int j = mt * 16 + q * 4 + r;
            pk[r] = bf16r(fsilu(acc[mt][r] + s_bn1[j]));
        }
        *(s4v*)&mid[eRow][mt * 16 + q * 4] = pk;
    }

    // GEMM2'': Wn2T . mid + bn2, then z = h + upd, LayerNorm
    f32x4 acc2[8];
    #pragma unroll
    for (int mt = 0; mt < 8; mt++) acc2[mt] = (f32x4){0.f, 0.f, 0.f, 0.f};
    for (int k0 = 0; k0 < 128; k0 += 32) {
        s8v bf = *(const s8v*)&mid[eRow][k0 + kq];
        #pragma unroll
        for (int mt = 0; mt < 8; mt++) {
            s8v af = *(const s8v*)(wn2t + (mt * 16 + t16) * 128 + k0 + kq);
            acc2[mt] = __builtin_amdgcn_mfma_f32_16x16x32_bf16(af, bf, acc2[mt], 0, 0, 0);
        }
    }
    float zsum = 0.f, zsq = 0.f;
    #pragma unroll
    for (int mt = 0; mt < 8; mt++) {
        s4v hv = *(const s4v*)&feat[eRow][mt * 16 + q * 4];
        #pragma unroll
        for (int r = 0; r < 4; r++) {
            int j = mt * 16 + q * 4 + r;
            float z = b2f(hv[r]) + acc2[mt][r] + s_bn2[j];
            acc2[mt][r] = z;
            zsum += z;
            zsq += z * z;
        }
    }
    zsum += __shfl_xor(zsum, 16); zsum += __shfl_xor(zsum, 32);
    zsq  += __shfl_xor(zsq, 16);  zsq  += __shfl_xor(zsq, 32);
    float mu = zsum * (1.f / 128.f);
    float var = zsq * (1.f / 128.f) - mu * mu;
    float rstd = rsqrtf(fmaxf(var, 0.f) + 1e-5f);
    int node = n0 + eRow;
    if (node < NN) {
        if (outf32) {
            float* o = (float*)out + (long)node * 128;
            #pragma unroll
            for (int mt = 0; mt < 8; mt++) {
                float4 pk;
                pk.x = (acc2[mt][0] - mu) * rstd * s_g[mt * 16 + q * 4 + 0] + s_b[mt * 16 + q * 4 + 0];
                pk.y = (acc2[mt][1] - mu) * rstd * s_g[mt * 16 + q * 4 + 1] + s_b[mt * 16 + q * 4 + 1];
                pk.z = (acc2[mt][2] - mu) * rstd * s_g[mt * 16 + q * 4 + 2] + s_b[mt * 16 + q * 4 + 2];
                pk.w = (acc2[mt][3] - mu) * rstd * s_g[mt * 16 + q * 4 + 3] + s_b[mt * 16 + q * 4 + 3];
                *(float4*)&o[mt * 16 + q * 4] = pk;
            }
        } else {
            short* o = (short*)out + (long)node * 128;
            #pragma unroll
            for (int mt = 0; mt < 8; mt++) {
                s4v pk;
                #pragma unroll
                for (int r = 0; r < 4; r++) {
                    int j = mt * 16 + q * 4 + r;
                    pk[r] = bf16r((acc2[mt][r] - mu) * rstd * s_g[j] + s_b[j]);
                }
                *(s4v*)&o[mt * 16 + q * 4] = pk;
            }
        }
    }
}

// ---------------- x_new = x + agg_coord ----------------
__global__ void xnew_kernel(const float* __restrict__ xf, const float* __restrict__ aggCoord,
                            const int* __restrict__ flags, void* __restrict__ out) {
    int i = blockIdx.x * 256 + threadIdx.x;
    if (i >= NN * 3) return;
    float v = xf[i] + aggCoord[i];
    if (flags[0]) ((float*)out)[(long)NN * 128 + i] = v;
    else          ((short*)out)[(long)NN * 128 + i] = bf16r(v);
}

// ---------------- launch ----------------
extern "C" void kernel_launch(void* const* d_in, const int* in_sizes, int n_in,
                              void* d_out, int out_size, void* d_ws, size_t ws_size,
                              hipStream_t stream) {
    const void* h    = d_in[0];
    const void* x    = d_in[1];
    const void* ei   = d_in[2];
    const void* dist = d_in[3];
    const void* We1  = d_in[4];
    const void* be1  = d_in[5];
    const void* We2  = d_in[6];
    const void* be2  = d_in[7];
    const void* Wa   = d_in[8];
    const void* ba   = d_in[9];
    const void* Wn1  = d_in[10];
    const void* bn1  = d_in[11];
    const void* Wn2  = d_in[12];
    const void* bn2  = d_in[13];
    const void* Wc1  = d_in[14];
    const void* bc1  = d_in[15];
    const void* Wc2  = d_in[16];
    const void* gmma = d_in[17];
    const void* beta = d_in[18];

    char* ws = (char*)d_ws;
    int*   flags   = (int*)ws;                        // @0       16 B
    short* we1t    = (short*)(ws + 1024);             // 135168 B
    short* we2t    = (short*)(ws + 137216);           // 32768
    short* wc1t    = (short*)(ws + 169984);           // 32768
    short* wn1t    = (short*)(ws + 202752);           // 65536
    short* wn2t    = (short*)(ws + 268288);           // 32768
    float* biasbuf = (float*)(ws + 301056);           // 5632
    short* hc      = (short*)(ws + 307200);           // 12.8 MB
    int*   eic     = (int*)(ws + 13414400);           // 6.4 MB
    float* distf   = (float*)(ws + 19814400);         // 3.2 MB
    float* xf      = (float*)(ws + 23014400);         // 0.6 MB
    float* aggMsg  = (float*)(ws + 23614400);         // 25.6 MB
    float* aggCoord= (float*)(ws + 49214400);         // 0.6 MB  (end ~49.8 MB)

    hipMemsetAsync(aggMsg, 0, (size_t)(NN * 128 + NN * 3) * sizeof(float), stream);
    detect_kernel<<<1, 256, 0, stream>>>((const unsigned*)h, (const unsigned*)ei, flags);
    convert_kernel<<<(6400000 + 1600000 + 800000 + 150000 + 255) / 256, 256, 0, stream>>>(
        h, x, ei, dist, flags, hc, eic, distf, xf);
    prep_weights<<<641, 256, 0, stream>>>(We1, We2, Wc1, Wn1, Wn2,
                                          be1, be2, bc1, Wa, ba, Wc2,
                                          bn1, bn2, gmma, beta, flags,
                                          we1t, we2t, wc1t, wn1t, wn2t, biasbuf);
    edge_kernel<<<EE / 64, 256, 0, stream>>>(hc, eic, distf, xf, we1t, we2t, wc1t,
                                             biasbuf, aggMsg, aggCoord);
    node_kernel<<<(NN + 63) / 64, 256, 0, stream>>>(hc, aggMsg, wn1t, wn2t, biasbuf,
                                                    flags, d_out);
    xnew_kernel<<<(NN * 3 + 255) / 256, 256, 0, stream>>>(xf, aggCoord, flags, d_out);
}

// Round 3
// 996.402 us; speedup vs baseline: 1.6876x; 1.6876x over previous
//
#include <hip/hip_runtime.h>
#include <hip/hip_bf16.h>
#include <stdint.h>

// ---------------- constants ----------------
#define NN 50000
#define EE 800000
#define HD 128

typedef __attribute__((ext_vector_type(8))) short s8v;   // 8 bf16 (4 VGPRs) mfma A/B frag
typedef __attribute__((ext_vector_type(4))) short s4v;   // 4 bf16 (8B)
typedef __attribute__((ext_vector_type(4))) float f32x4; // mfma C/D frag

__device__ inline float b2f(short s) {
    unsigned u = ((unsigned)(unsigned short)s) << 16;
    return __builtin_bit_cast(float, u);
}
__device__ inline short bf16r(float f) {
    unsigned u = __builtin_bit_cast(unsigned, f);
    unsigned r = (u + 0x7fffu + ((u >> 16) & 1u)) >> 16;
    return (short)r;
}
__device__ inline float fsilu(float v) { return v / (1.f + __expf(-v)); }

// flag-dependent raw loads
__device__ inline float ldw(const void* p, long i, bool f32) {
    return f32 ? ((const float*)p)[i] : b2f(((const short*)p)[i]);
}
__device__ inline short ldb(const void* p, long i, bool f32) {
    return f32 ? bf16r(((const float*)p)[i]) : ((const short*)p)[i];
}

// ---------------- dtype detection ----------------
__global__ void detect_kernel(const unsigned* __restrict__ h_raw,
                              const unsigned* __restrict__ ei_raw, int* flags) {
    __shared__ int cnt_f32, cnt_nz;
    int t = threadIdx.x;
    if (t == 0) { cnt_f32 = 0; cnt_nz = 0; }
    __syncthreads();
    unsigned u = h_raw[t];
    unsigned ex = (u >> 23) & 0xFFu;
    int isf = (ex >= 100u && ex <= 150u) ? 1 : 0;  // fp32 N(0,1) exponent range
    unsigned w = ei_raw[2 * t + 1];                // high word if int64
    int nz = (w != 0u) ? 1 : 0;
    atomicAdd(&cnt_f32, isf);
    atomicAdd(&cnt_nz, nz);
    __syncthreads();
    if (t == 0) {
        flags[0] = (cnt_f32 >= 128) ? 1 : 0;
        flags[1] = (cnt_nz < 8) ? 1 : 0;
    }
}

// ---------------- canonicalize big arrays (+ per-col histogram) ----------------
__global__ void convert_kernel(const void* __restrict__ h, const void* __restrict__ x,
                               const void* __restrict__ ei, const void* __restrict__ dist,
                               const int* __restrict__ flags,
                               short* __restrict__ hc, int* __restrict__ eic,
                               float* __restrict__ distf, float* __restrict__ xf,
                               int* __restrict__ cnt) {
    bool f32 = flags[0] != 0, i64 = flags[1] != 0;
    long id = (long)blockIdx.x * 256 + threadIdx.x;
    if (id < 6400000L) { hc[id] = ldb(h, id, f32); return; }
    id -= 6400000L;
    if (id < 1600000L) {
        int v = i64 ? (int)((const long long*)ei)[id] : ((const int*)ei)[id];
        eic[id] = v;
        if (id >= 800000L) atomicAdd(&cnt[v], 1);   // col histogram
        return;
    }
    id -= 1600000L;
    if (id < 800000L) { distf[id] = ldw(dist, id, f32); return; }
    id -= 800000L;
    if (id < 150000L) { xf[id] = ldw(x, id, f32); }
}

// ---------------- exclusive scan of cnt[50000] -> fillptr ----------------
__global__ __launch_bounds__(1024)
void scan_kernel(const int* __restrict__ cnt, int* __restrict__ fillptr) {
    __shared__ int psum[1024];
    const int CH = 49;  // 1024*49 >= 50000
    int t = threadIdx.x;
    int base = t * CH;
    int s = 0;
    for (int i = 0; i < CH; i++) { int idx = base + i; if (idx < NN) s += cnt[idx]; }
    psum[t] = s;
    __syncthreads();
    for (int off = 1; off < 1024; off <<= 1) {
        int v = psum[t];
        int add = (t >= off) ? psum[t - off] : 0;
        __syncthreads();
        psum[t] = v + add;
        __syncthreads();
    }
    int running = (t > 0) ? psum[t - 1] : 0;   // exclusive prefix
    for (int i = 0; i < CH; i++) {
        int idx = base + i;
        if (idx < NN) { fillptr[idx] = running; running += cnt[idx]; }
    }
}

// ---------------- scatter edge ids into col-grouped order ----------------
__global__ void scatter_kernel(const int* __restrict__ eic, int* __restrict__ fillptr,
                               int* __restrict__ eord) {
    int e = blockIdx.x * 256 + threadIdx.x;
    if (e >= EE) return;
    int c = eic[EE + e];
    int pos = atomicAdd(&fillptr[c], 1);
    eord[pos] = e;
}

// ---------------- weights transpose + bias canonicalize ----------------
__global__ void prep_weights(const void* we1, const void* we2, const void* wc1,
                             const void* wn1, const void* wn2,
                             const void* be1, const void* be2, const void* bc1,
                             const void* wa, const void* ba, const void* wc2,
                             const void* bn1, const void* bn2,
                             const void* gmma, const void* beta,
                             const int* __restrict__ flags,
                             short* __restrict__ we1t, short* __restrict__ we2t,
                             short* __restrict__ wc1t, short* __restrict__ wn1t,
                             short* __restrict__ wn2t, float* __restrict__ biasbuf) {
    bool f32 = flags[0] != 0;
    int b = blockIdx.x, t = threadIdx.x;
    if (b < 640) {
        int m = b >> 7, j = b & 127;
        switch (m) {
            case 0: for (int k = t; k < 257; k += 256) we1t[j * 264 + k] = ldb(we1, k * 128 + j, f32); break;
            case 1: if (t < 128) we2t[j * 128 + t] = ldb(we2, t * 128 + j, f32); break;
            case 2: if (t < 128) wc1t[j * 128 + t] = ldb(wc1, t * 128 + j, f32); break;
            case 3: wn1t[j * 256 + t] = ldb(wn1, t * 128 + j, f32); break;
            case 4: if (t < 128) wn2t[j * 128 + t] = ldb(wn2, t * 128 + j, f32); break;
        }
    } else if (t < 128) {
        biasbuf[t]         = ldw(be1, t, f32);
        biasbuf[128 + t]   = ldw(be2, t, f32);
        biasbuf[256 + t]   = ldw(bc1, t, f32);
        biasbuf[384 + t]   = ldw(wa, t, f32);
        biasbuf[512 + t]   = ldw(wc2, t, f32);
        biasbuf[768 + t]   = ldw(bn1, t, f32);
        biasbuf[896 + t]   = ldw(bn2, t, f32);
        biasbuf[1024 + t]  = ldw(gmma, t, f32);
        biasbuf[1152 + t]  = ldw(beta, t, f32);
        biasbuf[1280 + t]  = ldw(we1, 256 * 128 + t, f32);
        if (t == 0) biasbuf[640] = ldw(ba, 0, f32);
    }
}

// ---------------- fused edge kernel (col-grouped edges, LDS segmented reduce) ----------------
__global__ __launch_bounds__(256, 2)
void edge_kernel(const short* __restrict__ hc, const int* __restrict__ eic,
                 const float* __restrict__ distf, const float* __restrict__ xf,
                 const int* __restrict__ eord,
                 const short* __restrict__ we1t, const short* __restrict__ we2t,
                 const short* __restrict__ wc1t, const float* __restrict__ biasbuf,
                 float* __restrict__ aggMsg, float* __restrict__ aggCoord) {
    __shared__ short feat[64][264];    // [edge][k0..256]: h[row]++h[col]
    __shared__ short msgbuf[64][136];  // per-edge message tile (msg1 -> msg)
    __shared__ float s_dist[64];
    __shared__ float s_rel[64][3];
    __shared__ float s_cvec[64][3];
    __shared__ int   s_col[64];
    __shared__ int   s_eid[64];
    __shared__ float s_be1[128], s_be2[128], s_bc1[128], s_wa[128], s_w256[128], s_wc2[128];
    __shared__ float s_ba;

    const int tid = threadIdx.x;
    const int e0 = blockIdx.x * 64;

    if (tid < 64) s_eid[tid] = eord[e0 + tid];
    __syncthreads();

    if (tid < 64) {
        int e = s_eid[tid];
        int r = eic[e], c = eic[EE + e];
        s_col[tid] = c;
        s_dist[tid] = distf[e];
        #pragma unroll
        for (int i = 0; i < 3; i++) s_rel[tid][i] = xf[r * 3 + i] - xf[c * 3 + i];
    }
    if (tid < 128) {
        s_be1[tid] = biasbuf[tid];
        s_be2[tid] = biasbuf[128 + tid];
        s_bc1[tid] = biasbuf[256 + tid];
        s_wa[tid]  = biasbuf[384 + tid];
        s_wc2[tid] = biasbuf[512 + tid];
        s_w256[tid] = biasbuf[1280 + tid];
    }
    if (tid == 0) s_ba = biasbuf[640];

    // gather feat tile: 128 segments (edge,half) x 16 lanes x 16B
    {
        int lane16 = tid & 15, grp = tid >> 4;
        for (int s = grp; s < 128; s += 16) {
            int e = s >> 1, half = s & 1;
            int idx = eic[(half ? EE : 0) + s_eid[e]];
            uint4 v = ((const uint4*)(hc + (long)idx * 128))[lane16];
            *(uint4*)&feat[e][half * 128 + lane16 * 8] = v;
        }
    }
    __syncthreads();

    const int lane = tid & 63;
    const int wid  = tid >> 6;
    const int t16 = lane & 15, q = lane >> 4;
    const int eRow = wid * 16 + t16;
    const int kq = q * 8;

    // ---- GEMM1': msg1[j][e] = silu(We1T . featT + be1), K=257 ----
    f32x4 acc[8];
    #pragma unroll
    for (int mt = 0; mt < 8; mt++) acc[mt] = (f32x4){0.f, 0.f, 0.f, 0.f};
    for (int k0 = 0; k0 < 256; k0 += 32) {
        s8v bf = *(const s8v*)&feat[eRow][k0 + kq];
        #pragma unroll
        for (int mt = 0; mt < 8; mt++) {
            s8v af = *(const s8v*)(we1t + (mt * 16 + t16) * 264 + k0 + kq);
            acc[mt] = __builtin_amdgcn_mfma_f32_16x16x32_bf16(af, bf, acc[mt], 0, 0, 0);
        }
    }
    float distE = s_dist[eRow];
    #pragma unroll
    for (int mt = 0; mt < 8; mt++) {
        s4v pk;
        #pragma unroll
        for (int r = 0; r < 4; r++) {
            int j = mt * 16 + q * 4 + r;
            float v = acc[mt][r] + distE * s_w256[j] + s_be1[j];
            pk[r] = bf16r(fsilu(v));
        }
        *(s4v*)&msgbuf[eRow][mt * 16 + q * 4] = pk;
    }

    // ---- GEMM2': msg[j][e] = We2T . msg1 + be2 ----
    f32x4 acc2[8];
    #pragma unroll
    for (int mt = 0; mt < 8; mt++) acc2[mt] = (f32x4){0.f, 0.f, 0.f, 0.f};
    for (int k0 = 0; k0 < 128; k0 += 32) {
        s8v bf = *(const s8v*)&msgbuf[eRow][k0 + kq];
        #pragma unroll
        for (int mt = 0; mt < 8; mt++) {
            s8v af = *(const s8v*)(we2t + (mt * 16 + t16) * 128 + k0 + kq);
            acc2[mt] = __builtin_amdgcn_mfma_f32_16x16x32_bf16(af, bf, acc2[mt], 0, 0, 0);
        }
    }
    // attention: sigmoid(msg . Wa + ba), then msg *= attn
    float part = 0.f;
    #pragma unroll
    for (int mt = 0; mt < 8; mt++) {
        #pragma unroll
        for (int r = 0; r < 4; r++) {
            int j = mt * 16 + q * 4 + r;
            acc2[mt][r] += s_be2[j];
            part += acc2[mt][r] * s_wa[j];
        }
    }
    part += __shfl_xor(part, 16);
    part += __shfl_xor(part, 32);
    float attn = 1.f / (1.f + __expf(-(part + s_ba)));
    #pragma unroll
    for (int mt = 0; mt < 8; mt++) {
        s4v pk;
        #pragma unroll
        for (int r = 0; r < 4; r++) pk[r] = bf16r(acc2[mt][r] * attn);
        *(s4v*)&msgbuf[eRow][mt * 16 + q * 4] = pk;  // same wave's rows only -> no barrier
    }

    // ---- GEMM3': coord_w = silu(Wc1T . msg + bc1) . Wc2 ----
    f32x4 acc3[8];
    #pragma unroll
    for (int mt = 0; mt < 8; mt++) acc3[mt] = (f32x4){0.f, 0.f, 0.f, 0.f};
    for (int k0 = 0; k0 < 128; k0 += 32) {
        s8v bf = *(const s8v*)&msgbuf[eRow][k0 + kq];
        #pragma unroll
        for (int mt = 0; mt < 8; mt++) {
            s8v af = *(const s8v*)(wc1t + (mt * 16 + t16) * 128 + k0 + kq);
            acc3[mt] = __builtin_amdgcn_mfma_f32_16x16x32_bf16(af, bf, acc3[mt], 0, 0, 0);
        }
    }
    float part2 = 0.f;
    #pragma unroll
    for (int mt = 0; mt < 8; mt++) {
        #pragma unroll
        for (int r = 0; r < 4; r++) {
            int j = mt * 16 + q * 4 + r;
            part2 += fsilu(acc3[mt][r] + s_bc1[j]) * s_wc2[j];
        }
    }
    part2 += __shfl_xor(part2, 16);
    part2 += __shfl_xor(part2, 32);
    if (q == 0) {
        #pragma unroll
        for (int i = 0; i < 3; i++) s_cvec[eRow][i] = s_rel[eRow][i] * part2;
    }
    __syncthreads();

    // ---- segmented reduce over sorted cols: one atomic per (run, channel) ----
    if (tid < 128) {
        int j = tid;
        int runcol = s_col[0];
        float racc = 0.f;
        for (int e = 0; e < 64; e++) {
            int c = s_col[e];
            if (c != runcol) {
                unsafeAtomicAdd(&aggMsg[(long)runcol * 128 + j], racc);
                runcol = c; racc = 0.f;
            }
            racc += b2f(msgbuf[e][j]);
        }
        unsafeAtomicAdd(&aggMsg[(long)runcol * 128 + j], racc);
    } else if (tid < 131) {
        int i = tid - 128;
        int runcol = s_col[0];
        float racc = 0.f;
        for (int e = 0; e < 64; e++) {
            int c = s_col[e];
            if (c != runcol) {
                unsafeAtomicAdd(&aggCoord[(long)runcol * 3 + i], racc);
                runcol = c; racc = 0.f;
            }
            racc += s_cvec[e][i];
        }
        unsafeAtomicAdd(&aggCoord[(long)runcol * 3 + i], racc);
    }
}

// ---------------- fused node kernel: node MLP + residual + LayerNorm ----------------
__global__ __launch_bounds__(256, 2)
void node_kernel(const short* __restrict__ hc, const float* __restrict__ aggMsg,
                 const short* __restrict__ wn1t, const short* __restrict__ wn2t,
                 const float* __restrict__ biasbuf, const int* __restrict__ flags,
                 void* __restrict__ out) {
    __shared__ short feat[64][264];   // [node][h(128) ++ aggMsg(128)]
    __shared__ short mid[64][136];
    __shared__ float s_bn1[128], s_bn2[128], s_g[128], s_b[128];

    const int tid = threadIdx.x;
    const int n0 = blockIdx.x * 64;
    const bool outf32 = flags[0] != 0;

    if (tid < 128) {
        s_bn1[tid] = biasbuf[768 + tid];
        s_bn2[tid] = biasbuf[896 + tid];
        s_g[tid]   = biasbuf[1024 + tid];
        s_b[tid]   = biasbuf[1152 + tid];
    }
    {
        int lane16 = tid & 15, grp = tid >> 4;
        for (int s = grp; s < 64; s += 16) {
            int node = n0 + s; if (node >= NN) node = 0;
            uint4 v = ((const uint4*)(hc + (long)node * 128))[lane16];
            *(uint4*)&feat[s][lane16 * 8] = v;
        }
    }
    for (int s = tid; s < 64 * 32; s += 256) {
        int e = s >> 5, k4 = s & 31;
        int node = n0 + e; if (node >= NN) node = 0;
        float4 v = ((const float4*)(aggMsg + (long)node * 128))[k4];
        s4v pk = {bf16r(v.x), bf16r(v.y), bf16r(v.z), bf16r(v.w)};
        *(s4v*)&feat[e][128 + k4 * 4] = pk;
    }
    __syncthreads();

    const int lane = tid & 63;
    const int wid  = tid >> 6;
    const int t16 = lane & 15, q = lane >> 4;
    const int eRow = wid * 16 + t16;
    const int kq = q * 8;

    // GEMM1'': silu(Wn1T . featT + bn1), K=256
    f32x4 acc[8];
    #pragma unroll
    for (int mt = 0; mt < 8; mt++) acc[mt] = (f32x4){0.f, 0.f, 0.f, 0.f};
    for (int k0 = 0; k0 < 256; k0 += 32) {
        s8v bf = *(const s8v*)&feat[eRow][k0 + kq];
        #pragma unroll
        for (int mt = 0; mt < 8; mt++) {
            s8v af = *(const s8v*)(wn1t + (mt * 16 + t16) * 256 + k0 + kq);
            acc[mt] = __builtin_amdgcn_mfma_f32_16x16x32_bf16(af, bf, acc[mt], 0, 0, 0);
        }
    }
    #pragma unroll
    for (int mt = 0; mt < 8; mt++) {
        s4v pk;
        #pragma unroll
        for (int r = 0; r < 4; r++) {
            int j = mt * 16 + q * 4 + r;
            pk[r] = bf16r(fsilu(acc[mt][r] + s_bn1[j]));
        }
        *(s4v*)&mid[eRow][mt * 16 + q * 4] = pk;
    }

    // GEMM2'': Wn2T . mid + bn2, then z = h + upd, LayerNorm
    f32x4 acc2[8];
    #pragma unroll
    for (int mt = 0; mt < 8; mt++) acc2[mt] = (f32x4){0.f, 0.f, 0.f, 0.f};
    for (int k0 = 0; k0 < 128; k0 += 32) {
        s8v bf = *(const s8v*)&mid[eRow][k0 + kq];
        #pragma unroll
        for (int mt = 0; mt < 8; mt++) {
            s8v af = *(const s8v*)(wn2t + (mt * 16 + t16) * 128 + k0 + kq);
            acc2[mt] = __builtin_amdgcn_mfma_f32_16x16x32_bf16(af, bf, acc2[mt], 0, 0, 0);
        }
    }
    float zsum = 0.f, zsq = 0.f;
    #pragma unroll
    for (int mt = 0; mt < 8; mt++) {
        s4v hv = *(const s4v*)&feat[eRow][mt * 16 + q * 4];
        #pragma unroll
        for (int r = 0; r < 4; r++) {
            int j = mt * 16 + q * 4 + r;
            float z = b2f(hv[r]) + acc2[mt][r] + s_bn2[j];
            acc2[mt][r] = z;
            zsum += z;
            zsq += z * z;
        }
    }
    zsum += __shfl_xor(zsum, 16); zsum += __shfl_xor(zsum, 32);
    zsq  += __shfl_xor(zsq, 16);  zsq  += __shfl_xor(zsq, 32);
    float mu = zsum * (1.f / 128.f);
    float var = zsq * (1.f / 128.f) - mu * mu;
    float rstd = rsqrtf(fmaxf(var, 0.f) + 1e-5f);
    int node = n0 + eRow;
    if (node < NN) {
        if (outf32) {
            float* o = (float*)out + (long)node * 128;
            #pragma unroll
            for (int mt = 0; mt < 8; mt++) {
                float4 pk;
                pk.x = (acc2[mt][0] - mu) * rstd * s_g[mt * 16 + q * 4 + 0] + s_b[mt * 16 + q * 4 + 0];
                pk.y = (acc2[mt][1] - mu) * rstd * s_g[mt * 16 + q * 4 + 1] + s_b[mt * 16 + q * 4 + 1];
                pk.z = (acc2[mt][2] - mu) * rstd * s_g[mt * 16 + q * 4 + 2] + s_b[mt * 16 + q * 4 + 2];
                pk.w = (acc2[mt][3] - mu) * rstd * s_g[mt * 16 + q * 4 + 3] + s_b[mt * 16 + q * 4 + 3];
                *(float4*)&o[mt * 16 + q * 4] = pk;
            }
        } else {
            short* o = (short*)out + (long)node * 128;
            #pragma unroll
            for (int mt = 0; mt < 8; mt++) {
                s4v pk;
                #pragma unroll
                for (int r = 0; r < 4; r++) {
                    int j = mt * 16 + q * 4 + r;
                    pk[r] = bf16r((acc2[mt][r] - mu) * rstd * s_g[j] + s_b[j]);
                }
                *(s4v*)&o[mt * 16 + q * 4] = pk;
            }
        }
    }
}

// ---------------- x_new = x + agg_coord ----------------
__global__ void xnew_kernel(const float* __restrict__ xf, const float* __restrict__ aggCoord,
                            const int* __restrict__ flags, void* __restrict__ out) {
    int i = blockIdx.x * 256 + threadIdx.x;
    if (i >= NN * 3) return;
    float v = xf[i] + aggCoord[i];
    if (flags[0]) ((float*)out)[(long)NN * 128 + i] = v;
    else          ((short*)out)[(long)NN * 128 + i] = bf16r(v);
}

// ---------------- launch ----------------
extern "C" void kernel_launch(void* const* d_in, const int* in_sizes, int n_in,
                              void* d_out, int out_size, void* d_ws, size_t ws_size,
                              hipStream_t stream) {
    const void* h    = d_in[0];
    const void* x    = d_in[1];
    const void* ei   = d_in[2];
    const void* dist = d_in[3];
    const void* We1  = d_in[4];
    const void* be1  = d_in[5];
    const void* We2  = d_in[6];
    const void* be2  = d_in[7];
    const void* Wa   = d_in[8];
    const void* ba   = d_in[9];
    const void* Wn1  = d_in[10];
    const void* bn1  = d_in[11];
    const void* Wn2  = d_in[12];
    const void* bn2  = d_in[13];
    const void* Wc1  = d_in[14];
    const void* bc1  = d_in[15];
    const void* Wc2  = d_in[16];
    const void* gmma = d_in[17];
    const void* beta = d_in[18];

    char* ws = (char*)d_ws;
    int*   flags   = (int*)ws;                        // @0
    short* we1t    = (short*)(ws + 1024);
    short* we2t    = (short*)(ws + 137216);
    short* wc1t    = (short*)(ws + 169984);
    short* wn1t    = (short*)(ws + 202752);
    short* wn2t    = (short*)(ws + 268288);
    float* biasbuf = (float*)(ws + 301056);
    short* hc      = (short*)(ws + 307200);           // 12.8 MB
    int*   eic     = (int*)(ws + 13414400);           // 6.4 MB
    float* distf   = (float*)(ws + 19814400);         // 3.2 MB
    float* xf      = (float*)(ws + 23014400);         // 0.6 MB
    // contiguous zero region: aggMsg + aggCoord + cnt
    float* aggMsg  = (float*)(ws + 23614400);         // 25.6 MB
    float* aggCoord= (float*)(ws + 49214400);         // 0.6 MB
    int*   cnt     = (int*)(ws + 49814400);           // 0.2 MB
    int*   fillptr = (int*)(ws + 50014400);           // 0.2 MB
    int*   eord    = (int*)(ws + 50214400);           // 3.2 MB  (end ~53.4 MB)

    // zero aggMsg + aggCoord + cnt in one shot (contiguous)
    hipMemsetAsync(aggMsg, 0, (size_t)(NN * 128 + NN * 3 + NN) * sizeof(float), stream);
    detect_kernel<<<1, 256, 0, stream>>>((const unsigned*)h, (const unsigned*)ei, flags);
    convert_kernel<<<(6400000 + 1600000 + 800000 + 150000 + 255) / 256, 256, 0, stream>>>(
        h, x, ei, dist, flags, hc, eic, distf, xf, cnt);
    prep_weights<<<641, 256, 0, stream>>>(We1, We2, Wc1, Wn1, Wn2,
                                          be1, be2, bc1, Wa, ba, Wc2,
                                          bn1, bn2, gmma, beta, flags,
                                          we1t, we2t, wc1t, wn1t, wn2t, biasbuf);
    scan_kernel<<<1, 1024, 0, stream>>>(cnt, fillptr);
    scatter_kernel<<<(EE + 255) / 256, 256, 0, stream>>>(eic, fillptr, eord);
    edge_kernel<<<EE / 64, 256, 0, stream>>>(hc, eic, distf, xf, eord, we1t, we2t, wc1t,
                                             biasbuf, aggMsg, aggCoord);
    node_kernel<<<(NN + 63) / 64, 256, 0, stream>>>(hc, aggMsg, wn1t, wn2t, biasbuf,
                                                    flags, d_out);
    xnew_kernel<<<(NN * 3 + 255) / 256, 256, 0, stream>>>(xf, aggCoord, flags, d_out);
}

// Round 4
// 922.775 us; speedup vs baseline: 1.8223x; 1.0798x over previous
//
#include <hip/hip_runtime.h>
#include <hip/hip_bf16.h>
#include <stdint.h>

// ---------------- constants ----------------
#define NN 50000
#define EE 800000
#define HD 128

typedef __attribute__((ext_vector_type(8))) short s8v;   // 8 bf16 (4 VGPRs) mfma A/B frag
typedef __attribute__((ext_vector_type(4))) short s4v;   // 4 bf16 (8B)
typedef __attribute__((ext_vector_type(4))) float f32x4; // mfma C/D frag

__device__ inline float b2f(short s) {
    unsigned u = ((unsigned)(unsigned short)s) << 16;
    return __builtin_bit_cast(float, u);
}
__device__ inline short bf16r(float f) {
    unsigned u = __builtin_bit_cast(unsigned, f);
    unsigned r = (u + 0x7fffu + ((u >> 16) & 1u)) >> 16;
    return (short)r;
}
// packed f32x2 -> bf16x2 (v_cvt_pk_bf16_f32, RNE — identical rounding to bf16r)
__device__ inline s4v pack4(float a, float b, float c, float d) {
    union { __hip_bfloat162 h2[2]; s4v v; } u;
    u.h2[0] = __float22bfloat162_rn(make_float2(a, b));
    u.h2[1] = __float22bfloat162_rn(make_float2(c, d));
    return u.v;
}
__device__ inline float fsilu(float v) { return v / (1.f + __expf(-v)); }

// flag-dependent raw loads
__device__ inline float ldw(const void* p, long i, bool f32) {
    return f32 ? ((const float*)p)[i] : b2f(((const short*)p)[i]);
}
__device__ inline short ldb(const void* p, long i, bool f32) {
    return f32 ? bf16r(((const float*)p)[i]) : ((const short*)p)[i];
}

// ---------------- dtype detection ----------------
__global__ void detect_kernel(const unsigned* __restrict__ h_raw,
                              const unsigned* __restrict__ ei_raw, int* flags) {
    __shared__ int cnt_f32, cnt_nz;
    int t = threadIdx.x;
    if (t == 0) { cnt_f32 = 0; cnt_nz = 0; }
    __syncthreads();
    unsigned u = h_raw[t];
    unsigned ex = (u >> 23) & 0xFFu;
    int isf = (ex >= 100u && ex <= 150u) ? 1 : 0;  // fp32 N(0,1) exponent range
    unsigned w = ei_raw[2 * t + 1];                // high word if int64
    int nz = (w != 0u) ? 1 : 0;
    atomicAdd(&cnt_f32, isf);
    atomicAdd(&cnt_nz, nz);
    __syncthreads();
    if (t == 0) {
        flags[0] = (cnt_f32 >= 128) ? 1 : 0;
        flags[1] = (cnt_nz < 8) ? 1 : 0;
    }
}

// ---------------- canonicalize big arrays (+ per-col histogram) ----------------
__global__ void convert_kernel(const void* __restrict__ h, const void* __restrict__ x,
                               const void* __restrict__ ei, const void* __restrict__ dist,
                               const int* __restrict__ flags,
                               short* __restrict__ hc, int* __restrict__ eic,
                               float* __restrict__ distf, float* __restrict__ xf,
                               int* __restrict__ cnt) {
    bool f32 = flags[0] != 0, i64 = flags[1] != 0;
    long id = (long)blockIdx.x * 256 + threadIdx.x;
    if (id < 6400000L) { hc[id] = ldb(h, id, f32); return; }
    id -= 6400000L;
    if (id < 1600000L) {
        int v = i64 ? (int)((const long long*)ei)[id] : ((const int*)ei)[id];
        eic[id] = v;
        if (id >= 800000L) atomicAdd(&cnt[v], 1);   // col histogram
        return;
    }
    id -= 1600000L;
    if (id < 800000L) { distf[id] = ldw(dist, id, f32); return; }
    id -= 800000L;
    if (id < 150000L) { xf[id] = ldw(x, id, f32); }
}

// ---------------- exclusive scan of cnt[50000] -> fillptr ----------------
__global__ __launch_bounds__(1024)
void scan_kernel(const int* __restrict__ cnt, int* __restrict__ fillptr) {
    __shared__ int psum[1024];
    const int CH = 49;  // 1024*49 >= 50000
    int t = threadIdx.x;
    int base = t * CH;
    int s = 0;
    for (int i = 0; i < CH; i++) { int idx = base + i; if (idx < NN) s += cnt[idx]; }
    psum[t] = s;
    __syncthreads();
    for (int off = 1; off < 1024; off <<= 1) {
        int v = psum[t];
        int add = (t >= off) ? psum[t - off] : 0;
        __syncthreads();
        psum[t] = v + add;
        __syncthreads();
    }
    int running = (t > 0) ? psum[t - 1] : 0;   // exclusive prefix
    for (int i = 0; i < CH; i++) {
        int idx = base + i;
        if (idx < NN) { fillptr[idx] = running; running += cnt[idx]; }
    }
}

// ---------------- scatter edge ids into col-grouped order ----------------
__global__ void scatter_kernel(const int* __restrict__ eic, int* __restrict__ fillptr,
                               int* __restrict__ eord) {
    int e = blockIdx.x * 256 + threadIdx.x;
    if (e >= EE) return;
    int c = eic[EE + e];
    int pos = atomicAdd(&fillptr[c], 1);
    eord[pos] = e;
}

// ---------------- weights transpose + bias canonicalize ----------------
__global__ void prep_weights(const void* we1, const void* we2, const void* wc1,
                             const void* wn1, const void* wn2,
                             const void* be1, const void* be2, const void* bc1,
                             const void* wa, const void* ba, const void* wc2,
                             const void* bn1, const void* bn2,
                             const void* gmma, const void* beta,
                             const int* __restrict__ flags,
                             short* __restrict__ we1t, short* __restrict__ we2t,
                             short* __restrict__ wc1t, short* __restrict__ wn1t,
                             short* __restrict__ wn2t, float* __restrict__ biasbuf) {
    bool f32 = flags[0] != 0;
    int b = blockIdx.x, t = threadIdx.x;
    if (b < 640) {
        int m = b >> 7, j = b & 127;
        switch (m) {
            case 0: for (int k = t; k < 257; k += 256) we1t[j * 264 + k] = ldb(we1, k * 128 + j, f32); break;
            case 1: if (t < 128) we2t[j * 128 + t] = ldb(we2, t * 128 + j, f32); break;
            case 2: if (t < 128) wc1t[j * 128 + t] = ldb(wc1, t * 128 + j, f32); break;
            case 3: wn1t[j * 256 + t] = ldb(wn1, t * 128 + j, f32); break;
            case 4: if (t < 128) wn2t[j * 128 + t] = ldb(wn2, t * 128 + j, f32); break;
        }
    } else if (t < 128) {
        biasbuf[t]         = ldw(be1, t, f32);
        biasbuf[128 + t]   = ldw(be2, t, f32);
        biasbuf[256 + t]   = ldw(bc1, t, f32);
        biasbuf[384 + t]   = ldw(wa, t, f32);
        biasbuf[512 + t]   = ldw(wc2, t, f32);
        biasbuf[768 + t]   = ldw(bn1, t, f32);
        biasbuf[896 + t]   = ldw(bn2, t, f32);
        biasbuf[1024 + t]  = ldw(gmma, t, f32);
        biasbuf[1152 + t]  = ldw(beta, t, f32);
        biasbuf[1280 + t]  = ldw(we1, 256 * 128 + t, f32);
        if (t == 0) biasbuf[640] = ldw(ba, 0, f32);
    }
}

// ---------------- fused edge kernel (col-grouped edges, msg aliased into feat) ----------------
// LDS ~39.4 KB -> 4 blocks/CU. msg1/msg live in feat[e][0:128] (h[row] half, consumed
// by each wave's own GEMM1 k-loop before overwrite; waves only touch their own 16 rows).
__global__ __launch_bounds__(256, 4)
void edge_kernel(const short* __restrict__ hc, const int* __restrict__ eic,
                 const float* __restrict__ distf, const float* __restrict__ xf,
                 const int* __restrict__ eord,
                 const short* __restrict__ we1t, const short* __restrict__ we2t,
                 const short* __restrict__ wc1t, const float* __restrict__ biasbuf,
                 float* __restrict__ aggMsg, float* __restrict__ aggCoord) {
    __shared__ short feat[64][264];    // [edge][h_row(0:128) ++ h_col(128:256)]; cols 0:128 reused for msg
    __shared__ float s_dist[64];
    __shared__ float s_rel[64][3];
    __shared__ float s_cvec[64][3];
    __shared__ int   s_col[64];
    __shared__ int   s_row[64];
    __shared__ float s_be1[128], s_be2[128], s_bc1[128], s_wa[128], s_w256[128], s_wc2[128];
    __shared__ float s_ba;

    const int tid = threadIdx.x;
    const int e0 = blockIdx.x * 64;

    if (tid < 64) {
        int e = eord[e0 + tid];
        int r = eic[e], c = eic[EE + e];
        s_row[tid] = r;
        s_col[tid] = c;
        s_dist[tid] = distf[e];
        #pragma unroll
        for (int i = 0; i < 3; i++) s_rel[tid][i] = xf[r * 3 + i] - xf[c * 3 + i];
    }
    if (tid < 128) {
        s_be1[tid] = biasbuf[tid];
        s_be2[tid] = biasbuf[128 + tid];
        s_bc1[tid] = biasbuf[256 + tid];
        s_wa[tid]  = biasbuf[384 + tid];
        s_wc2[tid] = biasbuf[512 + tid];
        s_w256[tid] = biasbuf[1280 + tid];
    }
    if (tid == 0) s_ba = biasbuf[640];
    __syncthreads();

    // gather feat tile: 128 segments (edge,half) x 16 lanes x 16B; node idx from LDS
    {
        int lane16 = tid & 15, grp = tid >> 4;
        for (int s = grp; s < 128; s += 16) {
            int e = s >> 1, half = s & 1;
            int idx = half ? s_col[e] : s_row[e];
            uint4 v = ((const uint4*)(hc + (long)idx * 128))[lane16];
            *(uint4*)&feat[e][half * 128 + lane16 * 8] = v;
        }
    }
    __syncthreads();

    const int lane = tid & 63;
    const int wid  = tid >> 6;
    const int t16 = lane & 15, q = lane >> 4;
    const int eRow = wid * 16 + t16;
    const int kq = q * 8;

    // ---- GEMM1': msg1[j][e] = silu(We1T . featT + be1), K=257 ----
    f32x4 acc[8];
    #pragma unroll
    for (int mt = 0; mt < 8; mt++) acc[mt] = (f32x4){0.f, 0.f, 0.f, 0.f};
    for (int k0 = 0; k0 < 256; k0 += 32) {
        s8v bf = *(const s8v*)&feat[eRow][k0 + kq];
        #pragma unroll
        for (int mt = 0; mt < 8; mt++) {
            s8v af = *(const s8v*)(we1t + (mt * 16 + t16) * 264 + k0 + kq);
            acc[mt] = __builtin_amdgcn_mfma_f32_16x16x32_bf16(af, bf, acc[mt], 0, 0, 0);
        }
    }
    float distE = s_dist[eRow];
    #pragma unroll
    for (int mt = 0; mt < 8; mt++) {
        int jb = mt * 16 + q * 4;
        float v0 = fsilu(acc[mt][0] + distE * s_w256[jb + 0] + s_be1[jb + 0]);
        float v1 = fsilu(acc[mt][1] + distE * s_w256[jb + 1] + s_be1[jb + 1]);
        float v2 = fsilu(acc[mt][2] + distE * s_w256[jb + 2] + s_be1[jb + 2]);
        float v3 = fsilu(acc[mt][3] + distE * s_w256[jb + 3] + s_be1[jb + 3]);
        *(s4v*)&feat[eRow][jb] = pack4(v0, v1, v2, v3);   // own rows, in-order LDS
    }

    // ---- GEMM2': msg[j][e] = We2T . msg1 + be2 ----
    f32x4 acc2[8];
    #pragma unroll
    for (int mt = 0; mt < 8; mt++) acc2[mt] = (f32x4){0.f, 0.f, 0.f, 0.f};
    for (int k0 = 0; k0 < 128; k0 += 32) {
        s8v bf = *(const s8v*)&feat[eRow][k0 + kq];
        #pragma unroll
        for (int mt = 0; mt < 8; mt++) {
            s8v af = *(const s8v*)(we2t + (mt * 16 + t16) * 128 + k0 + kq);
            acc2[mt] = __builtin_amdgcn_mfma_f32_16x16x32_bf16(af, bf, acc2[mt], 0, 0, 0);
        }
    }
    // attention: sigmoid(msg . Wa + ba), then msg *= attn
    float part = 0.f;
    #pragma unroll
    for (int mt = 0; mt < 8; mt++) {
        #pragma unroll
        for (int r = 0; r < 4; r++) {
            int j = mt * 16 + q * 4 + r;
            acc2[mt][r] += s_be2[j];
            part += acc2[mt][r] * s_wa[j];
        }
    }
    part += __shfl_xor(part, 16);
    part += __shfl_xor(part, 32);
    float attn = 1.f / (1.f + __expf(-(part + s_ba)));
    #pragma unroll
    for (int mt = 0; mt < 8; mt++) {
        int jb = mt * 16 + q * 4;
        *(s4v*)&feat[eRow][jb] = pack4(acc2[mt][0] * attn, acc2[mt][1] * attn,
                                       acc2[mt][2] * attn, acc2[mt][3] * attn);
    }

    // ---- GEMM3': coord_w = silu(Wc1T . msg + bc1) . Wc2 ----
    f32x4 acc3[8];
    #pragma unroll
    for (int mt = 0; mt < 8; mt++) acc3[mt] = (f32x4){0.f, 0.f, 0.f, 0.f};
    for (int k0 = 0; k0 < 128; k0 += 32) {
        s8v bf = *(const s8v*)&feat[eRow][k0 + kq];
        #pragma unroll
        for (int mt = 0; mt < 8; mt++) {
            s8v af = *(const s8v*)(wc1t + (mt * 16 + t16) * 128 + k0 + kq);
            acc3[mt] = __builtin_amdgcn_mfma_f32_16x16x32_bf16(af, bf, acc3[mt], 0, 0, 0);
        }
    }
    float part2 = 0.f;
    #pragma unroll
    for (int mt = 0; mt < 8; mt++) {
        #pragma unroll
        for (int r = 0; r < 4; r++) {
            int j = mt * 16 + q * 4 + r;
            part2 += fsilu(acc3[mt][r] + s_bc1[j]) * s_wc2[j];
        }
    }
    part2 += __shfl_xor(part2, 16);
    part2 += __shfl_xor(part2, 32);
    if (q == 0) {
        #pragma unroll
        for (int i = 0; i < 3; i++) s_cvec[eRow][i] = s_rel[eRow][i] * part2;
    }
    __syncthreads();

    // ---- segmented reduce over sorted cols (all 256 threads; wave-uniform branch) ----
    {
        int j = tid & 127;
        int eh = (tid >> 7) * 32;    // half: edges [eh, eh+32)
        int runcol = s_col[eh];
        float racc = 0.f;
        for (int e = eh; e < eh + 32; e++) {
            int c = s_col[e];
            if (c != runcol) {
                unsafeAtomicAdd(&aggMsg[(long)runcol * 128 + j], racc);
                runcol = c; racc = 0.f;
            }
            racc += b2f(feat[e][j]);
        }
        unsafeAtomicAdd(&aggMsg[(long)runcol * 128 + j], racc);
    }
    if (tid < 24) {
        int i = tid % 3, sl = tid / 3;      // 8 slices of 8 edges
        int eh = sl * 8;
        int runcol = s_col[eh];
        float racc = 0.f;
        for (int e = eh; e < eh + 8; e++) {
            int c = s_col[e];
            if (c != runcol) {
                unsafeAtomicAdd(&aggCoord[(long)runcol * 3 + i], racc);
                runcol = c; racc = 0.f;
            }
            racc += s_cvec[e][i];
        }
        unsafeAtomicAdd(&aggCoord[(long)runcol * 3 + i], racc);
    }
}

// ---------------- fused node kernel: node MLP + residual + LayerNorm ----------------
// mid aliased into feat[.][0:128]; residual h pre-read into registers.
__global__ __launch_bounds__(256, 4)
void node_kernel(const short* __restrict__ hc, const float* __restrict__ aggMsg,
                 const short* __restrict__ wn1t, const short* __restrict__ wn2t,
                 const float* __restrict__ biasbuf, const int* __restrict__ flags,
                 void* __restrict__ out) {
    __shared__ short feat[64][264];   // [node][h(0:128) ++ aggMsg(128:256)]; 0:128 reused for mid
    __shared__ float s_bn1[128], s_bn2[128], s_g[128], s_b[128];

    const int tid = threadIdx.x;
    const int n0 = blockIdx.x * 64;
    const bool outf32 = flags[0] != 0;

    if (tid < 128) {
        s_bn1[tid] = biasbuf[768 + tid];
        s_bn2[tid] = biasbuf[896 + tid];
        s_g[tid]   = biasbuf[1024 + tid];
        s_b[tid]   = biasbuf[1152 + tid];
    }
    {
        int lane16 = tid & 15, grp = tid >> 4;
        for (int s = grp; s < 64; s += 16) {
            int node = n0 + s; if (node >= NN) node = 0;
            uint4 v = ((const uint4*)(hc + (long)node * 128))[lane16];
            *(uint4*)&feat[s][lane16 * 8] = v;
        }
    }
    for (int s = tid; s < 64 * 32; s += 256) {
        int e = s >> 5, k4 = s & 31;
        int node = n0 + e; if (node >= NN) node = 0;
        float4 v = ((const float4*)(aggMsg + (long)node * 128))[k4];
        *(s4v*)&feat[e][128 + k4 * 4] = pack4(v.x, v.y, v.z, v.w);
    }
    __syncthreads();

    const int lane = tid & 63;
    const int wid  = tid >> 6;
    const int t16 = lane & 15, q = lane >> 4;
    const int eRow = wid * 16 + t16;
    const int kq = q * 8;

    // GEMM1'': silu(Wn1T . featT + bn1), K=256
    f32x4 acc[8];
    #pragma unroll
    for (int mt = 0; mt < 8; mt++) acc[mt] = (f32x4){0.f, 0.f, 0.f, 0.f};
    for (int k0 = 0; k0 < 256; k0 += 32) {
        s8v bf = *(const s8v*)&feat[eRow][k0 + kq];
        #pragma unroll
        for (int mt = 0; mt < 8; mt++) {
            s8v af = *(const s8v*)(wn1t + (mt * 16 + t16) * 256 + k0 + kq);
            acc[mt] = __builtin_amdgcn_mfma_f32_16x16x32_bf16(af, bf, acc[mt], 0, 0, 0);
        }
    }
    // pre-read residual h (own rows) before overwriting with mid
    s4v hres[8];
    #pragma unroll
    for (int mt = 0; mt < 8; mt++) hres[mt] = *(const s4v*)&feat[eRow][mt * 16 + q * 4];
    #pragma unroll
    for (int mt = 0; mt < 8; mt++) {
        int jb = mt * 16 + q * 4;
        *(s4v*)&feat[eRow][jb] = pack4(fsilu(acc[mt][0] + s_bn1[jb + 0]),
                                       fsilu(acc[mt][1] + s_bn1[jb + 1]),
                                       fsilu(acc[mt][2] + s_bn1[jb + 2]),
                                       fsilu(acc[mt][3] + s_bn1[jb + 3]));
    }

    // GEMM2'': Wn2T . mid + bn2, then z = h + upd, LayerNorm
    f32x4 acc2[8];
    #pragma unroll
    for (int mt = 0; mt < 8; mt++) acc2[mt] = (f32x4){0.f, 0.f, 0.f, 0.f};
    for (int k0 = 0; k0 < 128; k0 += 32) {
        s8v bf = *(const s8v*)&feat[eRow][k0 + kq];
        #pragma unroll
        for (int mt = 0; mt < 8; mt++) {
            s8v af = *(const s8v*)(wn2t + (mt * 16 + t16) * 128 + k0 + kq);
            acc2[mt] = __builtin_amdgcn_mfma_f32_16x16x32_bf16(af, bf, acc2[mt], 0, 0, 0);
        }
    }
    float zsum = 0.f, zsq = 0.f;
    #pragma unroll
    for (int mt = 0; mt < 8; mt++) {
        #pragma unroll
        for (int r = 0; r < 4; r++) {
            int j = mt * 16 + q * 4 + r;
            float z = b2f(hres[mt][r]) + acc2[mt][r] + s_bn2[j];
            acc2[mt][r] = z;
            zsum += z;
            zsq += z * z;
        }
    }
    zsum += __shfl_xor(zsum, 16); zsum += __shfl_xor(zsum, 32);
    zsq  += __shfl_xor(zsq, 16);  zsq  += __shfl_xor(zsq, 32);
    float mu = zsum * (1.f / 128.f);
    float var = zsq * (1.f / 128.f) - mu * mu;
    float rstd = rsqrtf(fmaxf(var, 0.f) + 1e-5f);
    int node = n0 + eRow;
    if (node < NN) {
        if (outf32) {
            float* o = (float*)out + (long)node * 128;
            #pragma unroll
            for (int mt = 0; mt < 8; mt++) {
                int jb = mt * 16 + q * 4;
                float4 pk;
                pk.x = (acc2[mt][0] - mu) * rstd * s_g[jb + 0] + s_b[jb + 0];
                pk.y = (acc2[mt][1] - mu) * rstd * s_g[jb + 1] + s_b[jb + 1];
                pk.z = (acc2[mt][2] - mu) * rstd * s_g[jb + 2] + s_b[jb + 2];
                pk.w = (acc2[mt][3] - mu) * rstd * s_g[jb + 3] + s_b[jb + 3];
                *(float4*)&o[jb] = pk;
            }
        } else {
            short* o = (short*)out + (long)node * 128;
            #pragma unroll
            for (int mt = 0; mt < 8; mt++) {
                int jb = mt * 16 + q * 4;
                s4v pk = pack4((acc2[mt][0] - mu) * rstd * s_g[jb + 0] + s_b[jb + 0],
                               (acc2[mt][1] - mu) * rstd * s_g[jb + 1] + s_b[jb + 1],
                               (acc2[mt][2] - mu) * rstd * s_g[jb + 2] + s_b[jb + 2],
                               (acc2[mt][3] - mu) * rstd * s_g[jb + 3] + s_b[jb + 3]);
                *(s4v*)&o[jb] = pk;
            }
        }
    }
}

// ---------------- x_new = x + agg_coord ----------------
__global__ void xnew_kernel(const float* __restrict__ xf, const float* __restrict__ aggCoord,
                            const int* __restrict__ flags, void* __restrict__ out) {
    int i = blockIdx.x * 256 + threadIdx.x;
    if (i >= NN * 3) return;
    float v = xf[i] + aggCoord[i];
    if (flags[0]) ((float*)out)[(long)NN * 128 + i] = v;
    else          ((short*)out)[(long)NN * 128 + i] = bf16r(v);
}

// ---------------- launch ----------------
extern "C" void kernel_launch(void* const* d_in, const int* in_sizes, int n_in,
                              void* d_out, int out_size, void* d_ws, size_t ws_size,
                              hipStream_t stream) {
    const void* h    = d_in[0];
    const void* x    = d_in[1];
    const void* ei   = d_in[2];
    const void* dist = d_in[3];
    const void* We1  = d_in[4];
    const void* be1  = d_in[5];
    const void* We2  = d_in[6];
    const void* be2  = d_in[7];
    const void* Wa   = d_in[8];
    const void* ba   = d_in[9];
    const void* Wn1  = d_in[10];
    const void* bn1  = d_in[11];
    const void* Wn2  = d_in[12];
    const void* bn2  = d_in[13];
    const void* Wc1  = d_in[14];
    const void* bc1  = d_in[15];
    const void* Wc2  = d_in[16];
    const void* gmma = d_in[17];
    const void* beta = d_in[18];

    char* ws = (char*)d_ws;
    int*   flags   = (int*)ws;                        // @0
    short* we1t    = (short*)(ws + 1024);
    short* we2t    = (short*)(ws + 137216);
    short* wc1t    = (short*)(ws + 169984);
    short* wn1t    = (short*)(ws + 202752);
    short* wn2t    = (short*)(ws + 268288);
    float* biasbuf = (float*)(ws + 301056);
    short* hc      = (short*)(ws + 307200);           // 12.8 MB
    int*   eic     = (int*)(ws + 13414400);           // 6.4 MB
    float* distf   = (float*)(ws + 19814400);         // 3.2 MB
    float* xf      = (float*)(ws + 23014400);         // 0.6 MB
    // contiguous zero region: aggMsg + aggCoord + cnt
    float* aggMsg  = (float*)(ws + 23614400);         // 25.6 MB
    float* aggCoord= (float*)(ws + 49214400);         // 0.6 MB
    int*   cnt     = (int*)(ws + 49814400);           // 0.2 MB
    int*   fillptr = (int*)(ws + 50014400);           // 0.2 MB
    int*   eord    = (int*)(ws + 50214400);           // 3.2 MB  (end ~53.4 MB)

    hipMemsetAsync(aggMsg, 0, (size_t)(NN * 128 + NN * 3 + NN) * sizeof(float), stream);
    detect_kernel<<<1, 256, 0, stream>>>((const unsigned*)h, (const unsigned*)ei, flags);
    convert_kernel<<<(6400000 + 1600000 + 800000 + 150000 + 255) / 256, 256, 0, stream>>>(
        h, x, ei, dist, flags, hc, eic, distf, xf, cnt);
    prep_weights<<<641, 256, 0, stream>>>(We1, We2, Wc1, Wn1, Wn2,
                                          be1, be2, bc1, Wa, ba, Wc2,
                                          bn1, bn2, gmma, beta, flags,
                                          we1t, we2t, wc1t, wn1t, wn2t, biasbuf);
    scan_kernel<<<1, 1024, 0, stream>>>(cnt, fillptr);
    scatter_kernel<<<(EE + 255) / 256, 256, 0, stream>>>(eic, fillptr, eord);
    edge_kernel<<<EE / 64, 256, 0, stream>>>(hc, eic, distf, xf, eord, we1t, we2t, wc1t,
                                             biasbuf, aggMsg, aggCoord);
    node_kernel<<<(NN + 63) / 64, 256, 0, stream>>>(hc, aggMsg, wn1t, wn2t, biasbuf,
                                                    flags, d_out);
    xnew_kernel<<<(NN * 3 + 255) / 256, 256, 0, stream>>>(xf, aggCoord, flags, d_out);
}

// Round 9
// 798.064 us; speedup vs baseline: 2.1071x; 1.1563x over previous
//
#include <hip/hip_runtime.h>
#include <hip/hip_bf16.h>
#include <stdint.h>

// ---------------- constants ----------------
#define NN 50000
#define EE 800000
#define HD 128

typedef __attribute__((ext_vector_type(8))) short s8v;   // 8 bf16 (4 VGPRs) mfma A/B frag
typedef __attribute__((ext_vector_type(4))) short s4v;   // 4 bf16 (8B)
typedef __attribute__((ext_vector_type(4))) float f32x4; // mfma C/D frag

__device__ inline float b2f(short s) {
    unsigned u = ((unsigned)(unsigned short)s) << 16;
    return __builtin_bit_cast(float, u);
}
__device__ inline short bf16r(float f) {
    unsigned u = __builtin_bit_cast(unsigned, f);
    unsigned r = (u + 0x7fffu + ((u >> 16) & 1u)) >> 16;
    return (short)r;
}
__device__ inline s4v pack4(float a, float b, float c, float d) {
    union { __hip_bfloat162 h2[2]; s4v v; } u;
    u.h2[0] = __float22bfloat162_rn(make_float2(a, b));
    u.h2[1] = __float22bfloat162_rn(make_float2(c, d));
    return u.v;
}
__device__ inline s8v pack8(const float* v) {
    union { __hip_bfloat162 h2[4]; s8v v8; } u;
    #pragma unroll
    for (int i = 0; i < 4; i++) u.h2[i] = __float22bfloat162_rn(make_float2(v[2*i], v[2*i+1]));
    return u.v8;
}
__device__ inline float fsilu(float v) { return v / (1.f + __expf(-v)); }

__device__ inline float ldw(const void* p, long i, bool f32) {
    return f32 ? ((const float*)p)[i] : b2f(((const short*)p)[i]);
}
__device__ inline short ldb(const void* p, long i, bool f32) {
    return f32 ? bf16r(((const float*)p)[i]) : ((const short*)p)[i];
}
__device__ inline int ldi(const void* p, long i, bool i64) {
    return i64 ? (int)((const long long*)p)[i] : ((const int*)p)[i];
}

// ---------------- dtype detection ----------------
__global__ void detect_kernel(const unsigned* __restrict__ h_raw,
                              const unsigned* __restrict__ ei_raw, int* flags) {
    __shared__ int cnt_f32, cnt_nz;
    int t = threadIdx.x;
    if (t == 0) { cnt_f32 = 0; cnt_nz = 0; }
    __syncthreads();
    unsigned u = h_raw[t];
    unsigned ex = (u >> 23) & 0xFFu;
    int isf = (ex >= 100u && ex <= 150u) ? 1 : 0;
    unsigned w = ei_raw[2 * t + 1];
    int nz = (w != 0u) ? 1 : 0;
    atomicAdd(&cnt_f32, isf);
    atomicAdd(&cnt_nz, nz);
    __syncthreads();
    if (t == 0) {
        flags[0] = (cnt_f32 >= 128) ? 1 : 0;
        flags[1] = (cnt_nz < 8) ? 1 : 0;
    }
}

// ---------------- per-col histogram ----------------
__global__ void hist_kernel(const void* __restrict__ ei, const int* __restrict__ flags,
                            int* __restrict__ cnt) {
    int e = blockIdx.x * 256 + threadIdx.x;
    if (e >= EE) return;
    int c = ldi(ei, (long)EE + e, flags[1] != 0);
    atomicAdd(&cnt[c], 1);
}

// ---------------- exclusive scan of cnt[50000] -> fillptr ----------------
__global__ __launch_bounds__(1024)
void scan_kernel(const int* __restrict__ cnt, int* __restrict__ fillptr) {
    __shared__ int psum[1024];
    const int CH = 49;
    int t = threadIdx.x;
    int base = t * CH;
    int s = 0;
    for (int i = 0; i < CH; i++) { int idx = base + i; if (idx < NN) s += cnt[idx]; }
    psum[t] = s;
    __syncthreads();
    for (int off = 1; off < 1024; off <<= 1) {
        int v = psum[t];
        int add = (t >= off) ? psum[t - off] : 0;
        __syncthreads();
        psum[t] = v + add;
        __syncthreads();
    }
    int running = (t > 0) ? psum[t - 1] : 0;
    for (int i = 0; i < CH; i++) {
        int idx = base + i;
        if (idx < NN) { fillptr[idx] = running; running += cnt[idx]; }
    }
}

// ---------------- scatter edge ids into col-grouped order ----------------
__global__ void scatter_kernel(const void* __restrict__ ei, const int* __restrict__ flags,
                               int* __restrict__ fillptr, int* __restrict__ eord) {
    int e = blockIdx.x * 256 + threadIdx.x;
    if (e >= EE) return;
    int c = ldi(ei, (long)EE + e, flags[1] != 0);
    int pos = atomicAdd(&fillptr[c], 1);
    eord[pos] = e;
}

// ---------------- weights transpose + bias canonicalize ----------------
// FIXED R5 BUG: wn1t (128 rows) previously got 256 blocks (b in [512,768)) -> j up to 255
// overran wn1t by 64KB, clobbering wn2t AND biasbuf with a racing writer.
// Correct partition: we1tt 256 | we2t 128 | wc1t 128 | wn1t 128 | wn2t 128 | biasbuf 1 = 769 blocks.
__global__ void prep_weights(const void* we1, const void* we2, const void* wc1,
                             const void* wn1, const void* wn2,
                             const void* be1, const void* be2, const void* bc1,
                             const void* wa, const void* ba, const void* wc2,
                             const void* bn1, const void* bn2,
                             const void* gmma, const void* beta,
                             const int* __restrict__ flags,
                             short* __restrict__ we1tt, short* __restrict__ we2t,
                             short* __restrict__ wc1t, short* __restrict__ wn1t,
                             short* __restrict__ wn2t, float* __restrict__ biasbuf) {
    bool f32 = flags[0] != 0;
    int b = blockIdx.x, t = threadIdx.x;
    if (b < 256) {
        if (t < 128) we1tt[b * 128 + t] = ldb(we1, (long)((b < 128 ? t : t + 128)) * 128 + (b & 127), f32);
    } else if (b < 384) {
        int j = b - 256; if (t < 128) we2t[j * 128 + t] = ldb(we2, t * 128 + j, f32);
    } else if (b < 512) {
        int j = b - 384; if (t < 128) wc1t[j * 128 + t] = ldb(wc1, t * 128 + j, f32);
    } else if (b < 640) {
        int j = b - 512; wn1t[j * 256 + t] = ldb(wn1, t * 128 + j, f32);   // j in [0,128)
    } else if (b < 768) {
        int j = b - 640; if (t < 128) wn2t[j * 128 + t] = ldb(wn2, t * 128 + j, f32);
    } else if (t < 128) {
        biasbuf[t]         = ldw(be1, t, f32);
        biasbuf[128 + t]   = ldw(be2, t, f32);
        biasbuf[256 + t]   = ldw(bc1, t, f32);
        biasbuf[384 + t]   = ldw(wa, t, f32);
        biasbuf[512 + t]   = ldw(wc2, t, f32);
        biasbuf[768 + t]   = ldw(bn1, t, f32);
        biasbuf[896 + t]   = ldw(bn2, t, f32);
        biasbuf[1024 + t]  = ldw(gmma, t, f32);
        biasbuf[1152 + t]  = ldw(beta, t, f32);
        biasbuf[1280 + t]  = ldw(we1, 256 * 128 + t, f32);   // We1 dist row
        if (t == 0) biasbuf[640] = ldw(ba, 0, f32);
    }
}

// ---------------- P12 = [h@We1_top, h@We1_mid] per node (N x 256, bf16) ----------------
// Single-N proven GEMM shape: wave owns 16 nodes, two sequential 8-acc passes.
__global__ __launch_bounds__(256, 4)
void p12_kernel(const void* __restrict__ hraw, const int* __restrict__ flags,
                const short* __restrict__ we1tt, short* __restrict__ p12) {
    __shared__ short ht[64][136];
    const int tid = threadIdx.x;
    const int n0 = blockIdx.x * 64;
    const bool f32 = flags[0] != 0;
    for (int s = tid; s < 1024; s += 256) {
        int e = s >> 4, c8 = s & 15;
        int node = n0 + e; if (node >= NN) node = 0;
        if (f32) {
            const float* src = (const float*)hraw + (long)node * 128 + c8 * 8;
            float4 v0 = *(const float4*)src, v1 = *(const float4*)(src + 4);
            float vv[8] = {v0.x, v0.y, v0.z, v0.w, v1.x, v1.y, v1.z, v1.w};
            *(s8v*)&ht[e][c8 * 8] = pack8(vv);
        } else {
            uint4 v = *(const uint4*)((const short*)hraw + (long)node * 128 + c8 * 8);
            *(uint4*)&ht[e][c8 * 8] = v;
        }
    }
    __syncthreads();
    const int lane = tid & 63, wid = tid >> 6, t16 = lane & 15, q = lane >> 4, kq = q * 8;
    const int nRow = wid * 16 + t16;
    const int nd = n0 + nRow;

    f32x4 acc[8];
    #pragma unroll
    for (int mt = 0; mt < 8; mt++) acc[mt] = (f32x4){0.f, 0.f, 0.f, 0.f};
    for (int k0 = 0; k0 < 128; k0 += 32) {
        s8v bf = *(const s8v*)&ht[nRow][k0 + kq];
        #pragma unroll
        for (int mt = 0; mt < 8; mt++) {
            s8v af = *(const s8v*)(we1tt + (mt * 16 + t16) * 128 + k0 + kq);
            acc[mt] = __builtin_amdgcn_mfma_f32_16x16x32_bf16(af, bf, acc[mt], 0, 0, 0);
        }
    }
    if (nd < NN) {
        #pragma unroll
        for (int mt = 0; mt < 8; mt++) {
            int j = mt * 16 + q * 4;
            *(s4v*)(p12 + (long)nd * 256 + j) = pack4(acc[mt][0], acc[mt][1], acc[mt][2], acc[mt][3]);
        }
    }

    #pragma unroll
    for (int mt = 0; mt < 8; mt++) acc[mt] = (f32x4){0.f, 0.f, 0.f, 0.f};
    for (int k0 = 0; k0 < 128; k0 += 32) {
        s8v bf = *(const s8v*)&ht[nRow][k0 + kq];
        #pragma unroll
        for (int mt = 0; mt < 8; mt++) {
            s8v af = *(const s8v*)(we1tt + (128 + mt * 16 + t16) * 128 + k0 + kq);
            acc[mt] = __builtin_amdgcn_mfma_f32_16x16x32_bf16(af, bf, acc[mt], 0, 0, 0);
        }
    }
    if (nd < NN) {
        #pragma unroll
        for (int mt = 0; mt < 8; mt++) {
            int j = mt * 16 + q * 4;
            *(s4v*)(p12 + (long)nd * 256 + 128 + j) = pack4(acc[mt][0], acc[mt][1], acc[mt][2], acc[mt][3]);
        }
    }
}

// ---------------- fused edge kernel: R4-proven 64-edge scaffold, GEMM1 -> P12 staging ----------------
__global__ __launch_bounds__(256, 5)
void edge_kernel(const short* __restrict__ p12, const void* __restrict__ ei,
                 const void* __restrict__ dist, const void* __restrict__ x,
                 const int* __restrict__ eord, const int* __restrict__ flags,
                 const short* __restrict__ we2t, const short* __restrict__ wc1t,
                 const float* __restrict__ biasbuf,
                 float* __restrict__ aggMsg, float* __restrict__ aggCoord) {
    __shared__ short msgbuf[64][136];   // msg1 -> msg (in place, per-wave rows)
    __shared__ float s_dist[64];
    __shared__ float s_rel[64][3];
    __shared__ float s_cvec[64][3];
    __shared__ int   s_col[64];
    __shared__ int   s_row[64];
    __shared__ float s_be1[128], s_w256[128], s_be2[128], s_wa[128], s_bc1[128], s_wc2[128];
    __shared__ float s_ba;

    const int tid = threadIdx.x;
    const int e0 = blockIdx.x * 64;
    const bool f32 = flags[0] != 0;
    const bool i64 = flags[1] != 0;

    if (tid < 64) {
        int e = eord[e0 + tid];
        int r = ldi(ei, e, i64), c = ldi(ei, (long)EE + e, i64);
        s_row[tid] = r;
        s_col[tid] = c;
        s_dist[tid] = ldw(dist, e, f32);
        #pragma unroll
        for (int i = 0; i < 3; i++)
            s_rel[tid][i] = ldw(x, (long)r * 3 + i, f32) - ldw(x, (long)c * 3 + i, f32);
    }
    if (tid < 128) {
        s_be1[tid]  = biasbuf[tid];
        s_be2[tid]  = biasbuf[128 + tid];
        s_bc1[tid]  = biasbuf[256 + tid];
        s_wa[tid]   = biasbuf[384 + tid];
        s_wc2[tid]  = biasbuf[512 + tid];
        s_w256[tid] = biasbuf[1280 + tid];
    }
    if (tid == 0) s_ba = biasbuf[640];
    __syncthreads();

    // staging: msg1 = silu(P1[row] + P2[col] + dist*w256 + be1); 1024 16B-chunks
    for (int s = tid; s < 1024; s += 256) {
        int e = s >> 4, jb = (s & 15) * 8;
        s8v a = *(const s8v*)(p12 + ((long)s_row[e] << 8) + jb);
        s8v b = *(const s8v*)(p12 + ((long)s_col[e] << 8) + 128 + jb);
        float de = s_dist[e];
        float vv[8];
        #pragma unroll
        for (int i = 0; i < 8; i++)
            vv[i] = fsilu(b2f(a[i]) + b2f(b[i]) + de * s_w256[jb + i] + s_be1[jb + i]);
        *(s8v*)&msgbuf[e][jb] = pack8(vv);
    }
    __syncthreads();

    const int lane = tid & 63;
    const int wid  = tid >> 6;
    const int t16 = lane & 15, q = lane >> 4;
    const int eRow = wid * 16 + t16;
    const int kq = q * 8;

    // ---- GEMM2': msg[j][e] = We2T . msg1 + be2 ----
    f32x4 acc2[8];
    #pragma unroll
    for (int mt = 0; mt < 8; mt++) acc2[mt] = (f32x4){0.f, 0.f, 0.f, 0.f};
    for (int k0 = 0; k0 < 128; k0 += 32) {
        s8v bf = *(const s8v*)&msgbuf[eRow][k0 + kq];
        #pragma unroll
        for (int mt = 0; mt < 8; mt++) {
            s8v af = *(const s8v*)(we2t + (mt * 16 + t16) * 128 + k0 + kq);
            acc2[mt] = __builtin_amdgcn_mfma_f32_16x16x32_bf16(af, bf, acc2[mt], 0, 0, 0);
        }
    }
    float part = 0.f;
    #pragma unroll
    for (int mt = 0; mt < 8; mt++) {
        #pragma unroll
        for (int r = 0; r < 4; r++) {
            int j = mt * 16 + q * 4 + r;
            acc2[mt][r] += s_be2[j];
            part += acc2[mt][r] * s_wa[j];
        }
    }
    part += __shfl_xor(part, 16);
    part += __shfl_xor(part, 32);
    float attn = 1.f / (1.f + __expf(-(part + s_ba)));
    #pragma unroll
    for (int mt = 0; mt < 8; mt++) {
        int jb = mt * 16 + q * 4;
        *(s4v*)&msgbuf[eRow][jb] = pack4(acc2[mt][0] * attn, acc2[mt][1] * attn,
                                         acc2[mt][2] * attn, acc2[mt][3] * attn);
    }

    // ---- GEMM3': coord_w = silu(Wc1T . msg + bc1) . Wc2 ----
    f32x4 acc3[8];
    #pragma unroll
    for (int mt = 0; mt < 8; mt++) acc3[mt] = (f32x4){0.f, 0.f, 0.f, 0.f};
    for (int k0 = 0; k0 < 128; k0 += 32) {
        s8v bf = *(const s8v*)&msgbuf[eRow][k0 + kq];
        #pragma unroll
        for (int mt = 0; mt < 8; mt++) {
            s8v af = *(const s8v*)(wc1t + (mt * 16 + t16) * 128 + k0 + kq);
            acc3[mt] = __builtin_amdgcn_mfma_f32_16x16x32_bf16(af, bf, acc3[mt], 0, 0, 0);
        }
    }
    float part2 = 0.f;
    #pragma unroll
    for (int mt = 0; mt < 8; mt++) {
        #pragma unroll
        for (int r = 0; r < 4; r++) {
            int j = mt * 16 + q * 4 + r;
            part2 += fsilu(acc3[mt][r] + s_bc1[j]) * s_wc2[j];
        }
    }
    part2 += __shfl_xor(part2, 16);
    part2 += __shfl_xor(part2, 32);
    if (q == 0) {
        #pragma unroll
        for (int i = 0; i < 3; i++) s_cvec[eRow][i] = s_rel[eRow][i] * part2;
    }
    __syncthreads();

    // ---- segmented reduce over sorted cols ----
    {
        int j = tid & 127;
        int eh = (tid >> 7) * 32;
        int runcol = s_col[eh];
        float racc = 0.f;
        for (int e = eh; e < eh + 32; e++) {
            int c = s_col[e];
            if (c != runcol) {
                unsafeAtomicAdd(&aggMsg[(long)runcol * 128 + j], racc);
                runcol = c; racc = 0.f;
            }
            racc += b2f(msgbuf[e][j]);
        }
        unsafeAtomicAdd(&aggMsg[(long)runcol * 128 + j], racc);
    }
    if (tid < 24) {
        int i = tid % 3, sl = tid / 3;
        int eh = sl * 8;
        int runcol = s_col[eh];
        float racc = 0.f;
        for (int e = eh; e < eh + 8; e++) {
            int c = s_col[e];
            if (c != runcol) {
                unsafeAtomicAdd(&aggCoord[(long)runcol * 3 + i], racc);
                runcol = c; racc = 0.f;
            }
            racc += s_cvec[e][i];
        }
        unsafeAtomicAdd(&aggCoord[(long)runcol * 3 + i], racc);
    }
}

// ---------------- fused node kernel: node MLP + residual + LayerNorm ----------------
__global__ __launch_bounds__(256, 4)
void node_kernel(const void* __restrict__ hraw, const float* __restrict__ aggMsg,
                 const short* __restrict__ wn1t, const short* __restrict__ wn2t,
                 const float* __restrict__ biasbuf, const int* __restrict__ flags,
                 void* __restrict__ out) {
    __shared__ short feat[64][264];   // [node][h(0:128) ++ aggMsg(128:256)]; 0:128 reused for mid
    __shared__ float s_bn1[128], s_bn2[128], s_g[128], s_b[128];

    const int tid = threadIdx.x;
    const int n0 = blockIdx.x * 64;
    const bool outf32 = flags[0] != 0;

    if (tid < 128) {
        s_bn1[tid] = biasbuf[768 + tid];
        s_bn2[tid] = biasbuf[896 + tid];
        s_g[tid]   = biasbuf[1024 + tid];
        s_b[tid]   = biasbuf[1152 + tid];
    }
    for (int s = tid; s < 1024; s += 256) {
        int e = s >> 4, c8 = s & 15;
        int node = n0 + e; if (node >= NN) node = 0;
        if (outf32) {
            const float* src = (const float*)hraw + (long)node * 128 + c8 * 8;
            float4 v0 = *(const float4*)src, v1 = *(const float4*)(src + 4);
            float vv[8] = {v0.x, v0.y, v0.z, v0.w, v1.x, v1.y, v1.z, v1.w};
            *(s8v*)&feat[e][c8 * 8] = pack8(vv);
        } else {
            uint4 v = *(const uint4*)((const short*)hraw + (long)node * 128 + c8 * 8);
            *(uint4*)&feat[e][c8 * 8] = v;
        }
    }
    for (int s = tid; s < 64 * 32; s += 256) {
        int e = s >> 5, k4 = s & 31;
        int node = n0 + e; if (node >= NN) node = 0;
        float4 v = ((const float4*)(aggMsg + (long)node * 128))[k4];
        *(s4v*)&feat[e][128 + k4 * 4] = pack4(v.x, v.y, v.z, v.w);
    }
    __syncthreads();

    const int lane = tid & 63;
    const int wid  = tid >> 6;
    const int t16 = lane & 15, q = lane >> 4;
    const int eRow = wid * 16 + t16;
    const int kq = q * 8;

    f32x4 acc[8];
    #pragma unroll
    for (int mt = 0; mt < 8; mt++) acc[mt] = (f32x4){0.f, 0.f, 0.f, 0.f};
    for (int k0 = 0; k0 < 256; k0 += 32) {
        s8v bf = *(const s8v*)&feat[eRow][k0 + kq];
        #pragma unroll
        for (int mt = 0; mt < 8; mt++) {
            s8v af = *(const s8v*)(wn1t + (mt * 16 + t16) * 256 + k0 + kq);
            acc[mt] = __builtin_amdgcn_mfma_f32_16x16x32_bf16(af, bf, acc[mt], 0, 0, 0);
        }
    }
    s4v hres[8];
    #pragma unroll
    for (int mt = 0; mt < 8; mt++) hres[mt] = *(const s4v*)&feat[eRow][mt * 16 + q * 4];
    #pragma unroll
    for (int mt = 0; mt < 8; mt++) {
        int jb = mt * 16 + q * 4;
        *(s4v*)&feat[eRow][jb] = pack4(fsilu(acc[mt][0] + s_bn1[jb + 0]),
                                       fsilu(acc[mt][1] + s_bn1[jb + 1]),
                                       fsilu(acc[mt][2] + s_bn1[jb + 2]),
                                       fsilu(acc[mt][3] + s_bn1[jb + 3]));
    }

    f32x4 acc2[8];
    #pragma unroll
    for (int mt = 0; mt < 8; mt++) acc2[mt] = (f32x4){0.f, 0.f, 0.f, 0.f};
    for (int k0 = 0; k0 < 128; k0 += 32) {
        s8v bf = *(const s8v*)&feat[eRow][k0 + kq];
        #pragma unroll
        for (int mt = 0; mt < 8; mt++) {
            s8v af = *(const s8v*)(wn2t + (mt * 16 + t16) * 128 + k0 + kq);
            acc2[mt] = __builtin_amdgcn_mfma_f32_16x16x32_bf16(af, bf, acc2[mt], 0, 0, 0);
        }
    }
    float zsum = 0.f, zsq = 0.f;
    #pragma unroll
    for (int mt = 0; mt < 8; mt++) {
        #pragma unroll
        for (int r = 0; r < 4; r++) {
            int j = mt * 16 + q * 4 + r;
            float z = b2f(hres[mt][r]) + acc2[mt][r] + s_bn2[j];
            acc2[mt][r] = z;
            zsum += z;
            zsq += z * z;
        }
    }
    zsum += __shfl_xor(zsum, 16); zsum += __shfl_xor(zsum, 32);
    zsq  += __shfl_xor(zsq, 16);  zsq  += __shfl_xor(zsq, 32);
    float mu = zsum * (1.f / 128.f);
    float var = zsq * (1.f / 128.f) - mu * mu;
    float rstd = rsqrtf(fmaxf(var, 0.f) + 1e-5f);
    int node = n0 + eRow;
    if (node < NN) {
        if (outf32) {
            float* o = (float*)out + (long)node * 128;
            #pragma unroll
            for (int mt = 0; mt < 8; mt++) {
                int jb = mt * 16 + q * 4;
                float4 pk;
                pk.x = (acc2[mt][0] - mu) * rstd * s_g[jb + 0] + s_b[jb + 0];
                pk.y = (acc2[mt][1] - mu) * rstd * s_g[jb + 1] + s_b[jb + 1];
                pk.z = (acc2[mt][2] - mu) * rstd * s_g[jb + 2] + s_b[jb + 2];
                pk.w = (acc2[mt][3] - mu) * rstd * s_g[jb + 3] + s_b[jb + 3];
                *(float4*)&o[jb] = pk;
            }
        } else {
            short* o = (short*)out + (long)node * 128;
            #pragma unroll
            for (int mt = 0; mt < 8; mt++) {
                int jb = mt * 16 + q * 4;
                s4v pk = pack4((acc2[mt][0] - mu) * rstd * s_g[jb + 0] + s_b[jb + 0],
                               (acc2[mt][1] - mu) * rstd * s_g[jb + 1] + s_b[jb + 1],
                               (acc2[mt][2] - mu) * rstd * s_g[jb + 2] + s_b[jb + 2],
                               (acc2[mt][3] - mu) * rstd * s_g[jb + 3] + s_b[jb + 3]);
                *(s4v*)&o[jb] = pk;
            }
        }
    }
}

// ---------------- x_new = x + agg_coord ----------------
__global__ void xnew_kernel(const void* __restrict__ x, const float* __restrict__ aggCoord,
                            const int* __restrict__ flags, void* __restrict__ out) {
    int i = blockIdx.x * 256 + threadIdx.x;
    if (i >= NN * 3) return;
    bool f32 = flags[0] != 0;
    float v = ldw(x, i, f32) + aggCoord[i];
    if (f32) ((float*)out)[(long)NN * 128 + i] = v;
    else     ((short*)out)[(long)NN * 128 + i] = bf16r(v);
}

// ---------------- launch ----------------
extern "C" void kernel_launch(void* const* d_in, const int* in_sizes, int n_in,
                              void* d_out, int out_size, void* d_ws, size_t ws_size,
                              hipStream_t stream) {
    const void* h    = d_in[0];
    const void* x    = d_in[1];
    const void* ei   = d_in[2];
    const void* dist = d_in[3];
    const void* We1  = d_in[4];
    const void* be1  = d_in[5];
    const void* We2  = d_in[6];
    const void* be2  = d_in[7];
    const void* Wa   = d_in[8];
    const void* ba   = d_in[9];
    const void* Wn1  = d_in[10];
    const void* bn1  = d_in[11];
    const void* Wn2  = d_in[12];
    const void* bn2  = d_in[13];
    const void* Wc1  = d_in[14];
    const void* bc1  = d_in[15];
    const void* Wc2  = d_in[16];
    const void* gmma = d_in[17];
    const void* beta = d_in[18];

    char* ws = (char*)d_ws;
    int*   flags   = (int*)ws;                          // @0
    short* we1tt   = (short*)(ws + 1024);               // 65536
    short* we2t    = (short*)(ws + 66560);              // 32768
    short* wc1t    = (short*)(ws + 99328);              // 32768
    short* wn1t    = (short*)(ws + 132096);             // 65536
    short* wn2t    = (short*)(ws + 197632);             // 32768
    float* biasbuf = (float*)(ws + 230400);             // 5632
    short* p12     = (short*)(ws + 236544);             // 25.6 MB -> 25836544
    float* aggMsg  = (float*)(ws + 25836544);           // 25.6 MB -> 51436544
    float* aggCoord= (float*)(ws + 51436544);           // 0.6 MB  -> 52036544
    int*   cnt     = (int*)(ws + 52036544);             // 0.2 MB  -> 52236544
    int*   fillptr = (int*)(ws + 52236544);             // 0.2 MB  -> 52436544
    int*   eord    = (int*)d_out;                       // 3.2 MB scratch; overwritten after edge_kernel

    hipMemsetAsync(aggMsg, 0, (size_t)(NN * 128 + NN * 3 + NN) * sizeof(float), stream);
    detect_kernel<<<1, 256, 0, stream>>>((const unsigned*)h, (const unsigned*)ei, flags);
    hist_kernel<<<(EE + 255) / 256, 256, 0, stream>>>(ei, flags, cnt);
    prep_weights<<<769, 256, 0, stream>>>(We1, We2, Wc1, Wn1, Wn2,
                                          be1, be2, bc1, Wa, ba, Wc2,
                                          bn1, bn2, gmma, beta, flags,
                                          we1tt, we2t, wc1t, wn1t, wn2t, biasbuf);
    scan_kernel<<<1, 1024, 0, stream>>>(cnt, fillptr);
    scatter_kernel<<<(EE + 255) / 256, 256, 0, stream>>>(ei, flags, fillptr, eord);
    p12_kernel<<<(NN + 63) / 64, 256, 0, stream>>>(h, flags, we1tt, p12);
    edge_kernel<<<EE / 64, 256, 0, stream>>>(p12, ei, dist, x, eord, flags,
                                             we2t, wc1t, biasbuf, aggMsg, aggCoord);
    node_kernel<<<(NN + 63) / 64, 256, 0, stream>>>(h, aggMsg, wn1t, wn2t, biasbuf,
                                                    flags, d_out);
    xnew_kernel<<<(NN * 3 + 255) / 256, 256, 0, stream>>>(x, aggCoord, flags, d_out);
}